// Round 7
// baseline (500.411 us; speedup 1.0000x reference)
//
#include <hip/hip_runtime.h>
#include <hip/hip_bf16.h>

#define BB 4
#define CC 256
#define CHH 128
#define NN 4096
#define KSHIFT 12.0f

typedef __attribute__((ext_vector_type(8))) short bf16x8;
typedef __attribute__((ext_vector_type(4))) float f32x4;

__device__ __forceinline__ float to_f(float v) { return v; }
__device__ __forceinline__ float to_f(__hip_bfloat16 v) { return __bfloat162float(v); }
__device__ __forceinline__ void st_f(float* p, float v) { *p = v; }
__device__ __forceinline__ void st_f(__hip_bfloat16* p, float v) { *p = __float2bfloat16(v); }
__device__ __forceinline__ unsigned short f2bf(float f) {
    __hip_bfloat16 h = __float2bfloat16(f);
    unsigned short u;
    __builtin_memcpy(&u, &h, 2);
    return u;
}
__device__ __forceinline__ bf16x8 ldb8(const unsigned short* p) { return *(const bf16x8*)p; }

// ---------------------------------------------------------------------------
// Kernel 0: wire-dtype detection (proven rounds 3-6 — keep).
// ---------------------------------------------------------------------------
__global__ void detect_kernel(const void* __restrict__ tb, int* __restrict__ flag) {
    if (threadIdx.x == 0) {
        const __hip_bfloat16* p = (const __hip_bfloat16*)tb;
        int big = 0, zeros = 0;
        for (int i = 0; i < 128; ++i) {
            float v = __bfloat162float(p[i]);
            if (!(fabsf(v) <= 0.5f)) big = 1;
            if ((i & 1) == 0 && v == 0.0f) zeros++;
        }
        *flag = (big || zeros >= 32) ? 1 : 0;
    }
}

// ---------------------------------------------------------------------------
// Kernel 1: convert all weights/biases once (proven round 6).
// ---------------------------------------------------------------------------
template <typename T>
__device__ __forceinline__ void prep_body(const T* tw, const T* fw, const T* gw, const T* ow,
                                          const T* tb2, const T* fb, const T* gb, const T* ob,
                                          unsigned short* Wb, unsigned short* OWb,
                                          float* Bf, float* OBf) {
    int idx = blockIdx.x * 256 + threadIdx.x;
    if (idx < 98304) {
        int cv = idx >> 15, rem = idx & 32767;
        const T* src = cv == 0 ? tw : (cv == 1 ? fw : gw);
        Wb[idx] = f2bf(to_f(src[rem]));
    } else if (idx < 131072) {
        OWb[idx - 98304] = f2bf(to_f(ow[idx - 98304]));
    } else if (idx < 131456) {
        int r = idx - 131072;
        int cv = r >> 7, j = r & 127;
        const T* src = cv == 0 ? tb2 : (cv == 1 ? fb : gb);
        Bf[r] = to_f(src[j]);
    } else if (idx < 131712) {
        OBf[idx - 131456] = to_f(ob[idx - 131456]);
    }
}

__global__ void prep_kernel(const void* tw, const void* fw, const void* gw, const void* ow,
                            const void* tb2, const void* fb, const void* gb, const void* ob,
                            const int* __restrict__ flag,
                            unsigned short* Wb, unsigned short* OWb, float* Bf, float* OBf) {
    if (*flag)
        prep_body<float>((const float*)tw, (const float*)fw, (const float*)gw, (const float*)ow,
                         (const float*)tb2, (const float*)fb, (const float*)gb, (const float*)ob,
                         Wb, OWb, Bf, OBf);
    else
        prep_body<__hip_bfloat16>((const __hip_bfloat16*)tw, (const __hip_bfloat16*)fw,
                                  (const __hip_bfloat16*)gw, (const __hip_bfloat16*)ow,
                                  (const __hip_bfloat16*)tb2, (const __hip_bfloat16*)fb,
                                  (const __hip_bfloat16*)gb, (const __hip_bfloat16*)ob,
                                  Wb, OWb, Bf, OBf);
}

// ---------------------------------------------------------------------------
// Kernel 2: xt[b][p][c] = bf16(x[b][c][p]) (proven round 6).
// ---------------------------------------------------------------------------
template <typename T>
__device__ __forceinline__ void xtrans_body(const T* __restrict__ x, unsigned short* __restrict__ xt) {
    int b = blockIdx.z;
    const T* in = x + (size_t)b * CC * NN;
    unsigned short* out = xt + (size_t)b * NN * CC;
    int p0 = blockIdx.x * 64, c0 = blockIdx.y * 64;
    __shared__ unsigned short t[64][68];
    int flat = threadIdx.x;
#pragma unroll
    for (int tt = 0; tt < 16; ++tt) {
        int id = flat + tt * 256;
        int rr = id >> 6, cc = id & 63;
        t[cc][rr] = f2bf(to_f(in[(size_t)(c0 + rr) * NN + p0 + cc]));
    }
    __syncthreads();
#pragma unroll
    for (int tt = 0; tt < 16; ++tt) {
        int id = flat + tt * 256;
        int pp = id >> 6, jj = id & 63;
        out[(size_t)(p0 + pp) * CC + c0 + jj] = t[pp][jj];
    }
}

__launch_bounds__(256)
__global__ void xtrans_kernel(const void* x, const int* __restrict__ flag,
                              unsigned short* __restrict__ xt) {
    if (*flag) xtrans_body<float>((const float*)x, xt);
    else       xtrans_body<__hip_bfloat16>((const __hip_bfloat16*)x, xt);
}

// ---------------------------------------------------------------------------
// Kernel 3: three 1x1 convs via MFMA (proven round 6).
// ---------------------------------------------------------------------------
__launch_bounds__(256)
__global__ void conv3_mfma_kernel(const unsigned short* __restrict__ xt,
                                  const unsigned short* __restrict__ Wb,
                                  const float* __restrict__ Bf,
                                  unsigned short* __restrict__ T1b,
                                  unsigned short* __restrict__ T2b,
                                  unsigned short* __restrict__ T3b) {
    int b = blockIdx.y;
    int p0 = blockIdx.x * 16;
    int flat = threadIdx.x;
    int w = flat >> 6, lane = flat & 63, m = lane & 15, quad = lane >> 4;
    const unsigned short* xrow = xt + ((size_t)b * NN + p0 + m) * CC;
    bf16x8 xf[8];
#pragma unroll
    for (int kc = 0; kc < 8; ++kc)
        xf[kc] = ldb8(&xrow[kc * 32 + quad * 8]);
    unsigned short* outs[3] = {T1b + (size_t)b * CHH * NN,
                               T2b + (size_t)b * CHH * NN,
                               T3b + (size_t)b * CHH * NN};
#pragma unroll
    for (int q = 0; q < 6; ++q) {
        int t = w * 6 + q;
        int cv = t >> 3, ot = t & 7;
        int o0 = ot * 16;
        const unsigned short* wrow = Wb + ((size_t)cv * CHH + o0 + m) * CC;
        f32x4 acc = {0.f, 0.f, 0.f, 0.f};
#pragma unroll
        for (int kc = 0; kc < 8; ++kc) {
            bf16x8 wf = ldb8(&wrow[kc * 32 + quad * 8]);
            acc = __builtin_amdgcn_mfma_f32_16x16x32_bf16(wf, xf[kc], acc, 0, 0, 0);
        }
#pragma unroll
        for (int r = 0; r < 4; ++r) {
            int o = o0 + quad * 4 + r;
            outs[cv][(size_t)o * NN + p0 + m] = f2bf(acc[r] + Bf[cv * CHH + o]);
        }
    }
}

// ---------------------------------------------------------------------------
// Kernel 4: generic bf16 tiled transpose (proven).
// ---------------------------------------------------------------------------
__launch_bounds__(256)
__global__ void transpose_kernel(const unsigned short* __restrict__ in,
                                 unsigned short* __restrict__ out, int R, int C) {
    int bz = blockIdx.z;
    in  += (size_t)bz * R * C;
    out += (size_t)bz * R * C;
    int c0 = blockIdx.x * 64, r0 = blockIdx.y * 64;
    __shared__ unsigned short t[64][68];
    int flat = threadIdx.x;
#pragma unroll
    for (int tt = 0; tt < 16; ++tt) {
        int id = flat + tt * 256;
        int r = id >> 6, c = id & 63;
        t[c][r] = in[(size_t)(r0 + r) * C + c0 + c];
    }
    __syncthreads();
#pragma unroll
    for (int tt = 0; tt < 16; ++tt) {
        int id = flat + tt * 256;
        int c = id >> 6, r = id & 63;
        out[(size_t)(c0 + c) * R + r0 + r] = t[c][r];
    }
}

// ---------------------------------------------------------------------------
// Kernel 5 (pass A): column sums of exp(S - K) via MFMA.
// ROUND 7: A-frag ping-pong prefetch (forces loads in flight across the MFMA
// chain) + 8 i-chunks (grid 2048 = 8 blocks/CU = 8 waves/SIMD).
// ---------------------------------------------------------------------------
__launch_bounds__(256)
__global__ void stats_mfma_kernel(const unsigned short* __restrict__ T1b,
                                  const unsigned short* __restrict__ T2t,
                                  float* __restrict__ Lpart) {
    int b = blockIdx.z;
    int ic0 = blockIdx.y * 512;
    int u0 = blockIdx.x * 64;
    int flat = threadIdx.x;
    int w = flat >> 6, lane = flat & 63;
    int m = lane & 15, quad = lane >> 4;
    const unsigned short* A  = T1b + (size_t)b * CHH * NN;
    const unsigned short* Bt = T2t + (size_t)b * CHH * NN;
    int u = u0 + w * 16 + m;
    bf16x8 bf[4];
#pragma unroll
    for (int kc = 0; kc < 4; ++kc)
        bf[kc] = ldb8(&Bt[(size_t)u * CHH + kc * 32 + quad * 8]);

    bf16x8 afA[4], afB[4];
    auto loadA = [&](bf16x8* dst, int i) {
#pragma unroll
        for (int kc = 0; kc < 4; ++kc)
            dst[kc] = ldb8(&A[(size_t)(i + m) * CHH + kc * 32 + quad * 8]);
    };
    float csum = 0.f;
    loadA(afA, ic0);
    for (int step = 0; step < 32; step += 2) {
        loadA(afB, ic0 + (step + 1) * 16);
        {
            f32x4 acc = {0.f, 0.f, 0.f, 0.f};
#pragma unroll
            for (int kc = 0; kc < 4; ++kc)
                acc = __builtin_amdgcn_mfma_f32_16x16x32_bf16(afA[kc], bf[kc], acc, 0, 0, 0);
#pragma unroll
            for (int r = 0; r < 4; ++r)
                csum += __expf(acc[r] - KSHIFT);
        }
        loadA(afA, ic0 + ((step + 2) & 31) * 16);   // wraps on last iter (redundant, safe)
        {
            f32x4 acc = {0.f, 0.f, 0.f, 0.f};
#pragma unroll
            for (int kc = 0; kc < 4; ++kc)
                acc = __builtin_amdgcn_mfma_f32_16x16x32_bf16(afB[kc], bf[kc], acc, 0, 0, 0);
#pragma unroll
            for (int r = 0; r < 4; ++r)
                csum += __expf(acc[r] - KSHIFT);
        }
    }
    csum += __shfl_xor(csum, 16, 64);
    csum += __shfl_xor(csum, 32, 64);
    if (lane < 16)
        Lpart[((size_t)blockIdx.y * BB + b) * NN + u] = csum;
}

// ---------------------------------------------------------------------------
// Kernel 6: LL[b][u] = K + log(sum of 8 chunk partials)
// ---------------------------------------------------------------------------
__global__ void lmerge_kernel(const float* __restrict__ Lpart, float* __restrict__ LL) {
    int idx = blockIdx.x * 256 + threadIdx.x;
    int b = idx >> 12, u = idx & 4095;
    float s = 0.f;
#pragma unroll
    for (int c = 0; c < 8; ++c)
        s += Lpart[((size_t)c * BB + b) * NN + u];
    LL[idx] = logf(s) + KSHIFT;
}

// ---------------------------------------------------------------------------
// Kernel 7 (pass B): Y = P @ X3 via MFMA.
// ROUND 7: u-tile 64 -> 32; Bt fragments PING-PONG prefetched one full
// iteration ahead; X3 fragments issued at iteration top (~300 cyc before
// use). Forces ~160 VGPR of in-flight loads instead of the round-6
// 48-VGPR serialized schedule (the 37K-cyc/iter stall).
// ---------------------------------------------------------------------------
__launch_bounds__(256)
__global__ void attn_mfma_kernel(const unsigned short* __restrict__ T1b,
                                 const unsigned short* __restrict__ T2t,
                                 const unsigned short* __restrict__ X3t,
                                 const float* __restrict__ LL,
                                 unsigned short* __restrict__ Ybf) {
    int b = blockIdx.y;
    int i0 = blockIdx.x * 16;
    int flat = threadIdx.x;
    int w = flat >> 6, lane = flat & 63;
    int m = lane & 15, quad = lane >> 4;
    const unsigned short* A  = T1b + (size_t)b * CHH * NN;
    const unsigned short* Bt = T2t + (size_t)b * CHH * NN;
    const unsigned short* X3 = X3t + (size_t)b * CHH * NN;
    const float* LLb = LL + (size_t)b * NN;
    __shared__ __align__(16) char smem[32768];
    unsigned short (*pT)[40] = (unsigned short (*)[40])(smem + w * 1280);  // [16][40] per wave
    float (*mb)[8][4][64] = (float (*)[8][4][64])smem;                     // merge buffer

    bf16x8 ath[4];
#pragma unroll
    for (int kc = 0; kc < 4; ++kc)
        ath[kc] = ldb8(&A[(size_t)(i0 + m) * CHH + kc * 32 + quad * 8]);
    f32x4 yacc[8];
#pragma unroll
    for (int js = 0; js < 8; ++js) yacc[js] = (f32x4){0.f, 0.f, 0.f, 0.f};

    int ubase = w * 1024;                           // this wave's u-chunk

    bf16x8 btA[8], btB[8];
    auto loadBT = [&](bf16x8* dst, int u0) {
#pragma unroll
        for (int t = 0; t < 8; ++t) {
            int s2 = t >> 2, kc = t & 3;
            dst[t] = ldb8(&Bt[(size_t)(u0 + s2 * 16 + m) * CHH + kc * 32 + quad * 8]);
        }
    };
    auto consume = [&](bf16x8* bt, int u0) {
        bf16x8 x3[8];                               // issued early: ~S-phase of lead time
#pragma unroll
        for (int js = 0; js < 8; ++js)
            x3[js] = ldb8(&X3[(size_t)(js * 16 + m) * NN + u0 + quad * 8]);
        f32x4 s0 = {0.f, 0.f, 0.f, 0.f}, s1 = {0.f, 0.f, 0.f, 0.f};
#pragma unroll
        for (int kc = 0; kc < 4; ++kc) {
            s0 = __builtin_amdgcn_mfma_f32_16x16x32_bf16(ath[kc], bt[kc], s0, 0, 0, 0);
            s1 = __builtin_amdgcn_mfma_f32_16x16x32_bf16(ath[kc], bt[4 + kc], s1, 0, 0, 0);
        }
        float ll0 = LLb[u0 + m];
        float ll1 = LLb[u0 + 16 + m];
#pragma unroll
        for (int r = 0; r < 4; ++r) {
            pT[quad * 4 + r][m]      = f2bf(__expf(s0[r] - ll0));
            pT[quad * 4 + r][16 + m] = f2bf(__expf(s1[r] - ll1));
        }
        bf16x8 pa = *(const bf16x8*)&pT[m][quad * 8];   // C->A layout hop (wave-private)
#pragma unroll
        for (int js = 0; js < 8; ++js)
            yacc[js] = __builtin_amdgcn_mfma_f32_16x16x32_bf16(pa, x3[js], yacc[js], 0, 0, 0);
    };

    loadBT(btA, ubase);
    for (int ut = 0; ut < 32; ut += 2) {
        int u0 = ubase + ut * 32;
        loadBT(btB, u0 + 32);
        consume(btA, u0);
        loadBT(btA, (ut == 30) ? ubase : (u0 + 64));    // wrap on last (redundant, safe)
        consume(btB, u0 + 32);
    }
    __syncthreads();                                // all pT reads done before mb overwrite
#pragma unroll
    for (int js = 0; js < 8; ++js)
#pragma unroll
        for (int r = 0; r < 4; ++r)
            mb[w][js][r][lane] = yacc[js][r];
    __syncthreads();
#pragma unroll
    for (int q = 0; q < 2; ++q) {
        int js = w * 2 + q;
#pragma unroll
        for (int r = 0; r < 4; ++r) {
            float v = mb[0][js][r][lane] + mb[1][js][r][lane] +
                      mb[2][js][r][lane] + mb[3][js][r][lane];
            Ybf[((size_t)b * NN + i0 + quad * 4 + r) * CHH + js * 16 + m] = f2bf(v);
        }
    }
}

// ---------------------------------------------------------------------------
// Kernel 8: out = x + out_w @ Y^T + out_b via MFMA (proven round 6).
// ---------------------------------------------------------------------------
template <typename T>
__device__ __forceinline__ void outconv_body(const T* __restrict__ x,
                                             const unsigned short* __restrict__ Yb,
                                             const unsigned short* __restrict__ OWb,
                                             const float* __restrict__ OBf,
                                             T* __restrict__ out) {
    int b = blockIdx.y;
    int p0 = blockIdx.x * 16;
    int flat = threadIdx.x;
    int w = flat >> 6, lane = flat & 63, m = lane & 15, quad = lane >> 4;
    const unsigned short* yrow = Yb + ((size_t)b * NN + p0 + m) * CHH;
    bf16x8 yf[4];
#pragma unroll
    for (int kc = 0; kc < 4; ++kc)
        yf[kc] = ldb8(&yrow[kc * 32 + quad * 8]);
#pragma unroll
    for (int q = 0; q < 4; ++q) {
        int o0 = (w * 4 + q) * 16;
        const unsigned short* wrow = OWb + (size_t)(o0 + m) * CHH;
        f32x4 acc = {0.f, 0.f, 0.f, 0.f};
#pragma unroll
        for (int kc = 0; kc < 4; ++kc) {
            bf16x8 aw = ldb8(&wrow[kc * 32 + quad * 8]);
            acc = __builtin_amdgcn_mfma_f32_16x16x32_bf16(aw, yf[kc], acc, 0, 0, 0);
        }
#pragma unroll
        for (int r = 0; r < 4; ++r) {
            int co = o0 + quad * 4 + r;
            size_t oi = ((size_t)b * CC + co) * NN + p0 + m;
            st_f(&out[oi], acc[r] + OBf[co] + to_f(x[oi]));
        }
    }
}

__launch_bounds__(256)
__global__ void outconv_mfma_kernel(const void* x, const unsigned short* __restrict__ Yb,
                                    const unsigned short* __restrict__ OWb,
                                    const float* __restrict__ OBf,
                                    const int* __restrict__ flag, void* out) {
    if (*flag)
        outconv_body<float>((const float*)x, Yb, OWb, OBf, (float*)out);
    else
        outconv_body<__hip_bfloat16>((const __hip_bfloat16*)x, Yb, OWb, OBf, (__hip_bfloat16*)out);
}

extern "C" void kernel_launch(void* const* d_in, const int* in_sizes, int n_in,
                              void* d_out, int out_size, void* d_ws, size_t ws_size,
                              hipStream_t stream) {
    const void* x  = d_in[0];
    const void* tw = d_in[1];
    const void* tb = d_in[2];
    const void* fw = d_in[3];
    const void* fb = d_in[4];
    const void* gw = d_in[5];
    const void* gb = d_in[6];
    const void* ow = d_in[7];
    const void* ob = d_in[8];

    // Workspace (~22 MB) with aliasing (proven round 6; Lpart grown to 8 chunks).
    const size_t TE = (size_t)BB * CHH * NN;        // 2,097,152
    unsigned short* T1b = (unsigned short*)d_ws;
    unsigned short* T2b = T1b + TE;
    unsigned short* T3b = T2b + TE;
    unsigned short* xt  = T3b + TE;                 // 2*TE shorts
    unsigned short* T2t = xt;                       // alias: low half of xt (dead after conv3)
    unsigned short* X3t = xt + TE;                  // alias: high half of xt
    unsigned short* Ybf = T2b;                      // alias: T2b dead after transpose
    unsigned short* Wb  = xt + 2 * TE;              // 98304 shorts
    unsigned short* OWb = Wb + 98304;               // 32768 shorts
    float* Bf    = (float*)(OWb + 32768);           // 384
    float* OBf   = Bf + 384;                        // 256
    float* Lpart = OBf + 256;                       // 8 * BB * NN = 131072
    float* LLb   = Lpart + 131072;                  // 16384
    int*   Flag  = (int*)(LLb + 16384);

    detect_kernel<<<1, 64, 0, stream>>>(tb, Flag);
    prep_kernel<<<dim3(515), 256, 0, stream>>>(tw, fw, gw, ow, tb, fb, gb, ob,
                                               Flag, Wb, OWb, Bf, OBf);
    xtrans_kernel<<<dim3(NN / 64, CC / 64, BB), 256, 0, stream>>>(x, Flag, xt);
    conv3_mfma_kernel<<<dim3(NN / 16, BB), 256, 0, stream>>>(xt, Wb, Bf, T1b, T2b, T3b);
    transpose_kernel<<<dim3(NN / 64, CHH / 64, BB), 256, 0, stream>>>(T2b, T2t, CHH, NN);
    transpose_kernel<<<dim3(CHH / 64, NN / 64, BB), 256, 0, stream>>>(T3b, X3t, NN, CHH);
    stats_mfma_kernel<<<dim3(NN / 64, 8, BB), 256, 0, stream>>>(T1b, T2t, Lpart);
    lmerge_kernel<<<dim3(BB * NN / 256), 256, 0, stream>>>(Lpart, LLb);
    attn_mfma_kernel<<<dim3(NN / 16, BB), 256, 0, stream>>>(T1b, T2t, X3t, LLb, Ybf);
    outconv_mfma_kernel<<<dim3(NN / 16, BB), 256, 0, stream>>>(x, Ybf, OWb, OBf, Flag, d_out);
}

// Round 8
// 288.712 us; speedup vs baseline: 1.7332x; 1.7332x over previous
//
#include <hip/hip_runtime.h>
#include <hip/hip_bf16.h>

#define BB 4
#define CC 256
#define CHH 128
#define NN 4096
#define KSHIFT 12.0f

typedef __attribute__((ext_vector_type(8))) short bf16x8;
typedef __attribute__((ext_vector_type(4))) float f32x4;

__device__ __forceinline__ float to_f(float v) { return v; }
__device__ __forceinline__ float to_f(__hip_bfloat16 v) { return __bfloat162float(v); }
__device__ __forceinline__ void st_f(float* p, float v) { *p = v; }
__device__ __forceinline__ void st_f(__hip_bfloat16* p, float v) { *p = __float2bfloat16(v); }
__device__ __forceinline__ unsigned short f2bf(float f) {
    __hip_bfloat16 h = __float2bfloat16(f);
    unsigned short u;
    __builtin_memcpy(&u, &h, 2);
    return u;
}
__device__ __forceinline__ bf16x8 ldb8(const unsigned short* p) { return *(const bf16x8*)p; }

// async global->LDS, 16 B per lane. LDS dest = wave-uniform base + lane*16
// (slot arithmetic below guarantees lane-contiguity per wave-instruction).
__device__ __forceinline__ void gload_lds16(const unsigned short* g, unsigned short* l) {
    __builtin_amdgcn_global_load_lds(
        (const __attribute__((address_space(1))) unsigned int*)g,
        (__attribute__((address_space(3))) unsigned int*)l, 16, 0, 0);
}

// ---------------------------------------------------------------------------
// Kernel 0: wire-dtype detection (proven rounds 3-7 — keep).
// ---------------------------------------------------------------------------
__global__ void detect_kernel(const void* __restrict__ tb, int* __restrict__ flag) {
    if (threadIdx.x == 0) {
        const __hip_bfloat16* p = (const __hip_bfloat16*)tb;
        int big = 0, zeros = 0;
        for (int i = 0; i < 128; ++i) {
            float v = __bfloat162float(p[i]);
            if (!(fabsf(v) <= 0.5f)) big = 1;
            if ((i & 1) == 0 && v == 0.0f) zeros++;
        }
        *flag = (big || zeros >= 32) ? 1 : 0;
    }
}

// ---------------------------------------------------------------------------
// Kernel 1: convert all weights/biases once (proven round 6).
// ---------------------------------------------------------------------------
template <typename T>
__device__ __forceinline__ void prep_body(const T* tw, const T* fw, const T* gw, const T* ow,
                                          const T* tb2, const T* fb, const T* gb, const T* ob,
                                          unsigned short* Wb, unsigned short* OWb,
                                          float* Bf, float* OBf) {
    int idx = blockIdx.x * 256 + threadIdx.x;
    if (idx < 98304) {
        int cv = idx >> 15, rem = idx & 32767;
        const T* src = cv == 0 ? tw : (cv == 1 ? fw : gw);
        Wb[idx] = f2bf(to_f(src[rem]));
    } else if (idx < 131072) {
        OWb[idx - 98304] = f2bf(to_f(ow[idx - 98304]));
    } else if (idx < 131456) {
        int r = idx - 131072;
        int cv = r >> 7, j = r & 127;
        const T* src = cv == 0 ? tb2 : (cv == 1 ? fb : gb);
        Bf[r] = to_f(src[j]);
    } else if (idx < 131712) {
        OBf[idx - 131456] = to_f(ob[idx - 131456]);
    }
}

__global__ void prep_kernel(const void* tw, const void* fw, const void* gw, const void* ow,
                            const void* tb2, const void* fb, const void* gb, const void* ob,
                            const int* __restrict__ flag,
                            unsigned short* Wb, unsigned short* OWb, float* Bf, float* OBf) {
    if (*flag)
        prep_body<float>((const float*)tw, (const float*)fw, (const float*)gw, (const float*)ow,
                         (const float*)tb2, (const float*)fb, (const float*)gb, (const float*)ob,
                         Wb, OWb, Bf, OBf);
    else
        prep_body<__hip_bfloat16>((const __hip_bfloat16*)tw, (const __hip_bfloat16*)fw,
                                  (const __hip_bfloat16*)gw, (const __hip_bfloat16*)ow,
                                  (const __hip_bfloat16*)tb2, (const __hip_bfloat16*)fb,
                                  (const __hip_bfloat16*)gb, (const __hip_bfloat16*)ob,
                                  Wb, OWb, Bf, OBf);
}

// ---------------------------------------------------------------------------
// Kernel 2: xt[b][p][c] = bf16(x[b][c][p]) (proven round 6).
// ---------------------------------------------------------------------------
template <typename T>
__device__ __forceinline__ void xtrans_body(const T* __restrict__ x, unsigned short* __restrict__ xt) {
    int b = blockIdx.z;
    const T* in = x + (size_t)b * CC * NN;
    unsigned short* out = xt + (size_t)b * NN * CC;
    int p0 = blockIdx.x * 64, c0 = blockIdx.y * 64;
    __shared__ unsigned short t[64][68];
    int flat = threadIdx.x;
#pragma unroll
    for (int tt = 0; tt < 16; ++tt) {
        int id = flat + tt * 256;
        int rr = id >> 6, cc = id & 63;
        t[cc][rr] = f2bf(to_f(in[(size_t)(c0 + rr) * NN + p0 + cc]));
    }
    __syncthreads();
#pragma unroll
    for (int tt = 0; tt < 16; ++tt) {
        int id = flat + tt * 256;
        int pp = id >> 6, jj = id & 63;
        out[(size_t)(p0 + pp) * CC + c0 + jj] = t[pp][jj];
    }
}

__launch_bounds__(256)
__global__ void xtrans_kernel(const void* x, const int* __restrict__ flag,
                              unsigned short* __restrict__ xt) {
    if (*flag) xtrans_body<float>((const float*)x, xt);
    else       xtrans_body<__hip_bfloat16>((const __hip_bfloat16*)x, xt);
}

// ---------------------------------------------------------------------------
// Kernel 3: three 1x1 convs via MFMA (proven round 6).
// ---------------------------------------------------------------------------
__launch_bounds__(256)
__global__ void conv3_mfma_kernel(const unsigned short* __restrict__ xt,
                                  const unsigned short* __restrict__ Wb,
                                  const float* __restrict__ Bf,
                                  unsigned short* __restrict__ T1b,
                                  unsigned short* __restrict__ T2b,
                                  unsigned short* __restrict__ T3b) {
    int b = blockIdx.y;
    int p0 = blockIdx.x * 16;
    int flat = threadIdx.x;
    int w = flat >> 6, lane = flat & 63, m = lane & 15, quad = lane >> 4;
    const unsigned short* xrow = xt + ((size_t)b * NN + p0 + m) * CC;
    bf16x8 xf[8];
#pragma unroll
    for (int kc = 0; kc < 8; ++kc)
        xf[kc] = ldb8(&xrow[kc * 32 + quad * 8]);
    unsigned short* outs[3] = {T1b + (size_t)b * CHH * NN,
                               T2b + (size_t)b * CHH * NN,
                               T3b + (size_t)b * CHH * NN};
#pragma unroll
    for (int q = 0; q < 6; ++q) {
        int t = w * 6 + q;
        int cv = t >> 3, ot = t & 7;
        int o0 = ot * 16;
        const unsigned short* wrow = Wb + ((size_t)cv * CHH + o0 + m) * CC;
        f32x4 acc = {0.f, 0.f, 0.f, 0.f};
#pragma unroll
        for (int kc = 0; kc < 8; ++kc) {
            bf16x8 wf = ldb8(&wrow[kc * 32 + quad * 8]);
            acc = __builtin_amdgcn_mfma_f32_16x16x32_bf16(wf, xf[kc], acc, 0, 0, 0);
        }
#pragma unroll
        for (int r = 0; r < 4; ++r) {
            int o = o0 + quad * 4 + r;
            outs[cv][(size_t)o * NN + p0 + m] = f2bf(acc[r] + Bf[cv * CHH + o]);
        }
    }
}

// ---------------------------------------------------------------------------
// Kernel 4: generic bf16 tiled transpose (proven).
// ---------------------------------------------------------------------------
__launch_bounds__(256)
__global__ void transpose_kernel(const unsigned short* __restrict__ in,
                                 unsigned short* __restrict__ out, int R, int C) {
    int bz = blockIdx.z;
    in  += (size_t)bz * R * C;
    out += (size_t)bz * R * C;
    int c0 = blockIdx.x * 64, r0 = blockIdx.y * 64;
    __shared__ unsigned short t[64][68];
    int flat = threadIdx.x;
#pragma unroll
    for (int tt = 0; tt < 16; ++tt) {
        int id = flat + tt * 256;
        int r = id >> 6, c = id & 63;
        t[c][r] = in[(size_t)(r0 + r) * C + c0 + c];
    }
    __syncthreads();
#pragma unroll
    for (int tt = 0; tt < 16; ++tt) {
        int id = flat + tt * 256;
        int c = id >> 6, r = id & 63;
        out[(size_t)(c0 + c) * R + r0 + r] = t[c][r];
    }
}

// ---------------------------------------------------------------------------
// Kernel 5 (pass A): colsum exp(S-K) — ROUND 8 REWRITE (LDS-staged, L2-local).
// Block = (64-u strip, i-half, batch). phi^T frags register-resident; theta
// staged per 64-i tile into swizzled LDS via global_load_lds; each byte
// fetched once per block (was: once per 16-row wave chunk).
// XCD pairing: batch = (blk&7)>>1 -> per-XCD working set ~1 MB (L2-resident).
// Grid 512 = 2 blocks/CU.
// ---------------------------------------------------------------------------
__launch_bounds__(256)
__global__ void stats_mfma_kernel(const unsigned short* __restrict__ T1b,
                                  const unsigned short* __restrict__ T2t,
                                  float* __restrict__ Lpart) {
    int blk = blockIdx.x;
    int b = (blk & 7) >> 1;
    int rest = (blk >> 3) * 2 + (blk & 1);   // 0..127 = strip*2 + ihalf
    int strip = rest >> 1, ih = rest & 1;
    int u0 = strip * 64;
    int ibase = ih * 2048;
    int flat = threadIdx.x;
    int w = flat >> 6, lane = flat & 63, m = lane & 15, quad = lane >> 4;
    const unsigned short* A  = T1b + (size_t)b * CHH * NN;
    const unsigned short* Bt = T2t + (size_t)b * CHH * NN;
    __shared__ unsigned short th[64 * 128];   // theta tile, swizzled [i][chunk']

    int u = u0 + w * 16 + m;
    bf16x8 bfr[4];
#pragma unroll
    for (int kc = 0; kc < 4; ++kc)
        bfr[kc] = ldb8(&Bt[(size_t)u * CHH + kc * 32 + quad * 8]);

    float csum = 0.f;
    for (int t = 0; t < 32; ++t) {           // 32 i-tiles of 64 in this half
        int i0t = ibase + t * 64;
        __syncthreads();                      // prev tile reads done
#pragma unroll
        for (int i = 0; i < 4; ++i) {         // stage 16 KB (4 wave-instr each)
            int sl = i * 256 + flat;          // = i*256 + w*64 + lane (contig/wave)
            int r = sl >> 4, ch = sl & 15;
            int c = ch ^ (r & 7);             // XOR swizzle (bank spread)
            gload_lds16(&A[(size_t)(i0t + r) * CHH + c * 8], &th[sl * 8]);
        }
        __syncthreads();                      // staging visible
#pragma unroll
        for (int s = 0; s < 4; ++s) {
            int irow = s * 16 + m;
            f32x4 acc = {0.f, 0.f, 0.f, 0.f};
#pragma unroll
            for (int kc = 0; kc < 4; ++kc) {
                int ch = (kc * 4 + quad) ^ (irow & 7);
                bf16x8 af = *(const bf16x8*)&th[irow * 128 + ch * 8];
                acc = __builtin_amdgcn_mfma_f32_16x16x32_bf16(af, bfr[kc], acc, 0, 0, 0);
            }
#pragma unroll
            for (int r = 0; r < 4; ++r)
                csum += __expf(acc[r] - KSHIFT);
        }
    }
    csum += __shfl_xor(csum, 16, 64);
    csum += __shfl_xor(csum, 32, 64);
    if (lane < 16)
        Lpart[((size_t)ih * BB + b) * NN + u] = csum;
}

// ---------------------------------------------------------------------------
// Kernel 6: LL[b][u] = K + log(sum of 2 i-half partials)
// ---------------------------------------------------------------------------
__global__ void lmerge_kernel(const float* __restrict__ Lpart, float* __restrict__ LL) {
    int idx = blockIdx.x * 256 + threadIdx.x;
    int b = idx >> 12, u = idx & 4095;
    float s = Lpart[(size_t)b * NN + u] + Lpart[((size_t)BB + b) * NN + u];
    LL[idx] = logf(s) + KSHIFT;
}

// ---------------------------------------------------------------------------
// Kernel 7 (pass B): Y = P @ X3 — ROUND 8 REWRITE (LDS-staged, L2-local).
// Block = 32 i-rows (2 waves x 16), loops ALL u in 64-tiles. Bt & X3 tiles
// (16 KB each) staged via global_load_lds with XOR source-swizzle; both
// waves reuse every staged byte. pT wave-private for the C->A layout hop.
// Traffic: 2.1 GB -> 1 GB; XCD pairing keeps per-XCD set ~3 MB (L2-hit).
// LDS 37.4 KB -> 4 blocks/CU. Grid 512 (128 i-tiles x 4 batches).
// ---------------------------------------------------------------------------
__launch_bounds__(128)
__global__ void attn_mfma_kernel(const unsigned short* __restrict__ T1b,
                                 const unsigned short* __restrict__ T2t,
                                 const unsigned short* __restrict__ X3t,
                                 const float* __restrict__ LL,
                                 unsigned short* __restrict__ Ybf) {
    int blk = blockIdx.x;
    int b = (blk & 7) >> 1;
    int it = (blk >> 3) * 2 + (blk & 1);     // 0..127 i32-tile
    int i0 = it * 32;
    int flat = threadIdx.x;                   // 0..127
    int w = flat >> 6, lane = flat & 63, m = lane & 15, quad = lane >> 4;
    const unsigned short* A  = T1b + (size_t)b * CHH * NN;
    const unsigned short* Bt = T2t + (size_t)b * CHH * NN;
    const unsigned short* X3 = X3t + (size_t)b * CHH * NN;
    const float* LLb = LL + (size_t)b * NN;

    __shared__ unsigned short bt[64 * 128];   // phi^T tile, swizzled [u][chunk']
    __shared__ unsigned short x3[128 * 64];   // X3 tile, swizzled [j][chunk']
    __shared__ unsigned short pT[2][16][72];  // wave-private P tiles

    int iw = i0 + w * 16;
    bf16x8 ath[4];
#pragma unroll
    for (int kc = 0; kc < 4; ++kc)
        ath[kc] = ldb8(&A[(size_t)(iw + m) * CHH + kc * 32 + quad * 8]);
    f32x4 yacc[8];
#pragma unroll
    for (int js = 0; js < 8; ++js) yacc[js] = (f32x4){0.f, 0.f, 0.f, 0.f};

    for (int u0 = 0; u0 < NN; u0 += 64) {
        __syncthreads();                      // prev tile reads done
#pragma unroll
        for (int i = 0; i < 8; ++i) {         // stage Bt tile (16 KB)
            int sl = i * 128 + flat;          // = i*128 + w*64 + lane (contig/wave)
            int u = sl >> 4, ch = sl & 15;
            int c = ch ^ (u & 7);
            gload_lds16(&Bt[(size_t)(u0 + u) * CHH + c * 8], &bt[sl * 8]);
        }
#pragma unroll
        for (int i = 0; i < 8; ++i) {         // stage X3 tile (16 KB)
            int sl = i * 128 + flat;
            int j = sl >> 3, ch = sl & 7;
            int c = ch ^ (j & 7);
            gload_lds16(&X3[(size_t)j * NN + u0 + c * 8], &x3[sl * 8]);
        }
        __syncthreads();                      // staging visible
        // ---- S phase: S(16i x 64u), exp, P -> wave-private LDS ----
#pragma unroll
        for (int s = 0; s < 4; ++s) {
            int u = s * 16 + m;
            f32x4 acc = {0.f, 0.f, 0.f, 0.f};
#pragma unroll
            for (int kc = 0; kc < 4; ++kc) {
                int ch = (kc * 4 + quad) ^ (u & 7);
                bf16x8 bf = *(const bf16x8*)&bt[u * 128 + ch * 8];
                acc = __builtin_amdgcn_mfma_f32_16x16x32_bf16(ath[kc], bf, acc, 0, 0, 0);
            }
            float ll = LLb[u0 + u];
#pragma unroll
            for (int r = 0; r < 4; ++r)
                pT[w][quad * 4 + r][s * 16 + m] = f2bf(__expf(acc[r] - ll));
        }
        // ---- PV phase: Y(16i x 128j) += P @ X3 ----
        bf16x8 pa0 = *(const bf16x8*)&pT[w][m][quad * 8];
        bf16x8 pa1 = *(const bf16x8*)&pT[w][m][32 + quad * 8];
#pragma unroll
        for (int js = 0; js < 8; ++js) {
            int j = js * 16 + m;
            int ch0 = quad ^ (j & 7);
            int ch1 = (4 + quad) ^ (j & 7);
            bf16x8 xb0 = *(const bf16x8*)&x3[j * 64 + ch0 * 8];
            bf16x8 xb1 = *(const bf16x8*)&x3[j * 64 + ch1 * 8];
            yacc[js] = __builtin_amdgcn_mfma_f32_16x16x32_bf16(pa0, xb0, yacc[js], 0, 0, 0);
            yacc[js] = __builtin_amdgcn_mfma_f32_16x16x32_bf16(pa1, xb1, yacc[js], 0, 0, 0);
        }
    }
#pragma unroll
    for (int js = 0; js < 8; ++js)
#pragma unroll
        for (int r = 0; r < 4; ++r)
            Ybf[((size_t)b * NN + iw + quad * 4 + r) * CHH + js * 16 + m] = f2bf(yacc[js][r]);
}

// ---------------------------------------------------------------------------
// Kernel 8: out = x + out_w @ Y^T + out_b via MFMA (proven round 6).
// ---------------------------------------------------------------------------
template <typename T>
__device__ __forceinline__ void outconv_body(const T* __restrict__ x,
                                             const unsigned short* __restrict__ Yb,
                                             const unsigned short* __restrict__ OWb,
                                             const float* __restrict__ OBf,
                                             T* __restrict__ out) {
    int b = blockIdx.y;
    int p0 = blockIdx.x * 16;
    int flat = threadIdx.x;
    int w = flat >> 6, lane = flat & 63, m = lane & 15, quad = lane >> 4;
    const unsigned short* yrow = Yb + ((size_t)b * NN + p0 + m) * CHH;
    bf16x8 yf[4];
#pragma unroll
    for (int kc = 0; kc < 4; ++kc)
        yf[kc] = ldb8(&yrow[kc * 32 + quad * 8]);
#pragma unroll
    for (int q = 0; q < 4; ++q) {
        int o0 = (w * 4 + q) * 16;
        const unsigned short* wrow = OWb + (size_t)(o0 + m) * CHH;
        f32x4 acc = {0.f, 0.f, 0.f, 0.f};
#pragma unroll
        for (int kc = 0; kc < 4; ++kc) {
            bf16x8 aw = ldb8(&wrow[kc * 32 + quad * 8]);
            acc = __builtin_amdgcn_mfma_f32_16x16x32_bf16(aw, yf[kc], acc, 0, 0, 0);
        }
#pragma unroll
        for (int r = 0; r < 4; ++r) {
            int co = o0 + quad * 4 + r;
            size_t oi = ((size_t)b * CC + co) * NN + p0 + m;
            st_f(&out[oi], acc[r] + OBf[co] + to_f(x[oi]));
        }
    }
}

__launch_bounds__(256)
__global__ void outconv_mfma_kernel(const void* x, const unsigned short* __restrict__ Yb,
                                    const unsigned short* __restrict__ OWb,
                                    const float* __restrict__ OBf,
                                    const int* __restrict__ flag, void* out) {
    if (*flag)
        outconv_body<float>((const float*)x, Yb, OWb, OBf, (float*)out);
    else
        outconv_body<__hip_bfloat16>((const __hip_bfloat16*)x, Yb, OWb, OBf, (__hip_bfloat16*)out);
}

extern "C" void kernel_launch(void* const* d_in, const int* in_sizes, int n_in,
                              void* d_out, int out_size, void* d_ws, size_t ws_size,
                              hipStream_t stream) {
    const void* x  = d_in[0];
    const void* tw = d_in[1];
    const void* tb = d_in[2];
    const void* fw = d_in[3];
    const void* fb = d_in[4];
    const void* gw = d_in[5];
    const void* gb = d_in[6];
    const void* ow = d_in[7];
    const void* ob = d_in[8];

    // Workspace (~22 MB) with aliasing (proven round 6; Lpart = 2 chunks now).
    const size_t TE = (size_t)BB * CHH * NN;        // 2,097,152
    unsigned short* T1b = (unsigned short*)d_ws;
    unsigned short* T2b = T1b + TE;
    unsigned short* T3b = T2b + TE;
    unsigned short* xt  = T3b + TE;                 // 2*TE shorts
    unsigned short* T2t = xt;                       // alias: low half of xt (dead after conv3)
    unsigned short* X3t = xt + TE;                  // alias: high half of xt
    unsigned short* Ybf = T2b;                      // alias: T2b dead after transpose
    unsigned short* Wb  = xt + 2 * TE;              // 98304 shorts
    unsigned short* OWb = Wb + 98304;               // 32768 shorts
    float* Bf    = (float*)(OWb + 32768);           // 384
    float* OBf   = Bf + 384;                        // 256
    float* Lpart = OBf + 256;                       // 2 * BB * NN = 32768
    float* LLb   = Lpart + 32768;                   // 16384
    int*   Flag  = (int*)(LLb + 16384);

    detect_kernel<<<1, 64, 0, stream>>>(tb, Flag);
    prep_kernel<<<dim3(515), 256, 0, stream>>>(tw, fw, gw, ow, tb, fb, gb, ob,
                                               Flag, Wb, OWb, Bf, OBf);
    xtrans_kernel<<<dim3(NN / 64, CC / 64, BB), 256, 0, stream>>>(x, Flag, xt);
    conv3_mfma_kernel<<<dim3(NN / 16, BB), 256, 0, stream>>>(xt, Wb, Bf, T1b, T2b, T3b);
    transpose_kernel<<<dim3(NN / 64, CHH / 64, BB), 256, 0, stream>>>(T2b, T2t, CHH, NN);
    transpose_kernel<<<dim3(CHH / 64, NN / 64, BB), 256, 0, stream>>>(T3b, X3t, NN, CHH);
    stats_mfma_kernel<<<dim3(512), 256, 0, stream>>>(T1b, T2t, Lpart);
    lmerge_kernel<<<dim3(BB * NN / 256), 256, 0, stream>>>(Lpart, LLb);
    attn_mfma_kernel<<<dim3(512), 128, 0, stream>>>(T1b, T2t, X3t, LLb, Ybf);
    outconv_mfma_kernel<<<dim3(NN / 16, BB), 256, 0, stream>>>(x, Ybf, OWb, OBf, Flag, d_out);
}

// Round 9
// 245.002 us; speedup vs baseline: 2.0425x; 1.1784x over previous
//
#include <hip/hip_runtime.h>
#include <hip/hip_bf16.h>

#define BB 4
#define CC 256
#define CHH 128
#define NN 4096
#define KSHIFT 12.0f

typedef __attribute__((ext_vector_type(8))) short bf16x8;
typedef __attribute__((ext_vector_type(4))) float f32x4;

__device__ __forceinline__ float to_f(float v) { return v; }
__device__ __forceinline__ float to_f(__hip_bfloat16 v) { return __bfloat162float(v); }
__device__ __forceinline__ void st_f(float* p, float v) { *p = v; }
__device__ __forceinline__ void st_f(__hip_bfloat16* p, float v) { *p = __float2bfloat16(v); }
__device__ __forceinline__ unsigned short f2bf(float f) {
    __hip_bfloat16 h = __float2bfloat16(f);
    unsigned short u;
    __builtin_memcpy(&u, &h, 2);
    return u;
}
__device__ __forceinline__ bf16x8 ldb8(const unsigned short* p) { return *(const bf16x8*)p; }

// async global->LDS, 16 B per lane. LDS dest = wave-uniform base + lane*16.
__device__ __forceinline__ void gload_lds16(const unsigned short* g, unsigned short* l) {
    __builtin_amdgcn_global_load_lds(
        (const __attribute__((address_space(1))) unsigned int*)g,
        (__attribute__((address_space(3))) unsigned int*)l, 16, 0, 0);
}

// ---------------------------------------------------------------------------
// Kernel 0: wire-dtype detection (proven rounds 3-8 — keep).
// ---------------------------------------------------------------------------
__global__ void detect_kernel(const void* __restrict__ tb, int* __restrict__ flag) {
    if (threadIdx.x == 0) {
        const __hip_bfloat16* p = (const __hip_bfloat16*)tb;
        int big = 0, zeros = 0;
        for (int i = 0; i < 128; ++i) {
            float v = __bfloat162float(p[i]);
            if (!(fabsf(v) <= 0.5f)) big = 1;
            if ((i & 1) == 0 && v == 0.0f) zeros++;
        }
        *flag = (big || zeros >= 32) ? 1 : 0;
    }
}

// ---------------------------------------------------------------------------
// Kernel 1: convert all weights/biases once (proven round 6).
// ---------------------------------------------------------------------------
template <typename T>
__device__ __forceinline__ void prep_body(const T* tw, const T* fw, const T* gw, const T* ow,
                                          const T* tb2, const T* fb, const T* gb, const T* ob,
                                          unsigned short* Wb, unsigned short* OWb,
                                          float* Bf, float* OBf) {
    int idx = blockIdx.x * 256 + threadIdx.x;
    if (idx < 98304) {
        int cv = idx >> 15, rem = idx & 32767;
        const T* src = cv == 0 ? tw : (cv == 1 ? fw : gw);
        Wb[idx] = f2bf(to_f(src[rem]));
    } else if (idx < 131072) {
        OWb[idx - 98304] = f2bf(to_f(ow[idx - 98304]));
    } else if (idx < 131456) {
        int r = idx - 131072;
        int cv = r >> 7, j = r & 127;
        const T* src = cv == 0 ? tb2 : (cv == 1 ? fb : gb);
        Bf[r] = to_f(src[j]);
    } else if (idx < 131712) {
        OBf[idx - 131456] = to_f(ob[idx - 131456]);
    }
}

__global__ void prep_kernel(const void* tw, const void* fw, const void* gw, const void* ow,
                            const void* tb2, const void* fb, const void* gb, const void* ob,
                            const int* __restrict__ flag,
                            unsigned short* Wb, unsigned short* OWb, float* Bf, float* OBf) {
    if (*flag)
        prep_body<float>((const float*)tw, (const float*)fw, (const float*)gw, (const float*)ow,
                         (const float*)tb2, (const float*)fb, (const float*)gb, (const float*)ob,
                         Wb, OWb, Bf, OBf);
    else
        prep_body<__hip_bfloat16>((const __hip_bfloat16*)tw, (const __hip_bfloat16*)fw,
                                  (const __hip_bfloat16*)gw, (const __hip_bfloat16*)ow,
                                  (const __hip_bfloat16*)tb2, (const __hip_bfloat16*)fb,
                                  (const __hip_bfloat16*)gb, (const __hip_bfloat16*)ob,
                                  Wb, OWb, Bf, OBf);
}

// ---------------------------------------------------------------------------
// Kernel 2: xt[b][p][c] = bf16(x[b][c][p]) (proven round 6).
// ---------------------------------------------------------------------------
template <typename T>
__device__ __forceinline__ void xtrans_body(const T* __restrict__ x, unsigned short* __restrict__ xt) {
    int b = blockIdx.z;
    const T* in = x + (size_t)b * CC * NN;
    unsigned short* out = xt + (size_t)b * NN * CC;
    int p0 = blockIdx.x * 64, c0 = blockIdx.y * 64;
    __shared__ unsigned short t[64][68];
    int flat = threadIdx.x;
#pragma unroll
    for (int tt = 0; tt < 16; ++tt) {
        int id = flat + tt * 256;
        int rr = id >> 6, cc = id & 63;
        t[cc][rr] = f2bf(to_f(in[(size_t)(c0 + rr) * NN + p0 + cc]));
    }
    __syncthreads();
#pragma unroll
    for (int tt = 0; tt < 16; ++tt) {
        int id = flat + tt * 256;
        int pp = id >> 6, jj = id & 63;
        out[(size_t)(p0 + pp) * CC + c0 + jj] = t[pp][jj];
    }
}

__launch_bounds__(256)
__global__ void xtrans_kernel(const void* x, const int* __restrict__ flag,
                              unsigned short* __restrict__ xt) {
    if (*flag) xtrans_body<float>((const float*)x, xt);
    else       xtrans_body<__hip_bfloat16>((const __hip_bfloat16*)x, xt);
}

// ---------------------------------------------------------------------------
// Kernel 3: three 1x1 convs via MFMA (proven round 6).
// ---------------------------------------------------------------------------
__launch_bounds__(256)
__global__ void conv3_mfma_kernel(const unsigned short* __restrict__ xt,
                                  const unsigned short* __restrict__ Wb,
                                  const float* __restrict__ Bf,
                                  unsigned short* __restrict__ T1b,
                                  unsigned short* __restrict__ T2b,
                                  unsigned short* __restrict__ T3b) {
    int b = blockIdx.y;
    int p0 = blockIdx.x * 16;
    int flat = threadIdx.x;
    int w = flat >> 6, lane = flat & 63, m = lane & 15, quad = lane >> 4;
    const unsigned short* xrow = xt + ((size_t)b * NN + p0 + m) * CC;
    bf16x8 xf[8];
#pragma unroll
    for (int kc = 0; kc < 8; ++kc)
        xf[kc] = ldb8(&xrow[kc * 32 + quad * 8]);
    unsigned short* outs[3] = {T1b + (size_t)b * CHH * NN,
                               T2b + (size_t)b * CHH * NN,
                               T3b + (size_t)b * CHH * NN};
#pragma unroll
    for (int q = 0; q < 6; ++q) {
        int t = w * 6 + q;
        int cv = t >> 3, ot = t & 7;
        int o0 = ot * 16;
        const unsigned short* wrow = Wb + ((size_t)cv * CHH + o0 + m) * CC;
        f32x4 acc = {0.f, 0.f, 0.f, 0.f};
#pragma unroll
        for (int kc = 0; kc < 8; ++kc) {
            bf16x8 wf = ldb8(&wrow[kc * 32 + quad * 8]);
            acc = __builtin_amdgcn_mfma_f32_16x16x32_bf16(wf, xf[kc], acc, 0, 0, 0);
        }
#pragma unroll
        for (int r = 0; r < 4; ++r) {
            int o = o0 + quad * 4 + r;
            outs[cv][(size_t)o * NN + p0 + m] = f2bf(acc[r] + Bf[cv * CHH + o]);
        }
    }
}

// ---------------------------------------------------------------------------
// Kernel 4: generic bf16 tiled transpose (proven).
// ---------------------------------------------------------------------------
__launch_bounds__(256)
__global__ void transpose_kernel(const unsigned short* __restrict__ in,
                                 unsigned short* __restrict__ out, int R, int C) {
    int bz = blockIdx.z;
    in  += (size_t)bz * R * C;
    out += (size_t)bz * R * C;
    int c0 = blockIdx.x * 64, r0 = blockIdx.y * 64;
    __shared__ unsigned short t[64][68];
    int flat = threadIdx.x;
#pragma unroll
    for (int tt = 0; tt < 16; ++tt) {
        int id = flat + tt * 256;
        int r = id >> 6, c = id & 63;
        t[c][r] = in[(size_t)(r0 + r) * C + c0 + c];
    }
    __syncthreads();
#pragma unroll
    for (int tt = 0; tt < 16; ++tt) {
        int id = flat + tt * 256;
        int c = id >> 6, r = id & 63;
        out[(size_t)(c0 + c) * R + r0 + r] = t[c][r];
    }
}

// ---------------------------------------------------------------------------
// Kernel 5 (pass A): colsum exp(S-K). ROUND 9: i-split x4 (grid 1024 ->
// 4 blocks/CU -> 4 waves/SIMD). Structure otherwise proven round 8.
// ---------------------------------------------------------------------------
__launch_bounds__(256)
__global__ void stats_mfma_kernel(const unsigned short* __restrict__ T1b,
                                  const unsigned short* __restrict__ T2t,
                                  float* __restrict__ Lpart) {
    int blk = blockIdx.x;
    int b = (blk & 7) >> 1;
    int rest = (blk >> 3) * 2 + (blk & 1);   // 0..255 = strip*4 + iq
    int strip = rest >> 2, iq = rest & 3;
    int u0 = strip * 64;
    int ibase = iq * 1024;
    int flat = threadIdx.x;
    int w = flat >> 6, lane = flat & 63, m = lane & 15, quad = lane >> 4;
    const unsigned short* A  = T1b + (size_t)b * CHH * NN;
    const unsigned short* Bt = T2t + (size_t)b * CHH * NN;
    __shared__ unsigned short th[64 * 128];   // theta tile, swizzled [i][chunk']

    int u = u0 + w * 16 + m;
    bf16x8 bfr[4];
#pragma unroll
    for (int kc = 0; kc < 4; ++kc)
        bfr[kc] = ldb8(&Bt[(size_t)u * CHH + kc * 32 + quad * 8]);

    float csum = 0.f;
    for (int t = 0; t < 16; ++t) {           // 16 i-tiles of 64 in this quarter
        int i0t = ibase + t * 64;
        __syncthreads();
#pragma unroll
        for (int i = 0; i < 4; ++i) {
            int sl = i * 256 + flat;
            int r = sl >> 4, ch = sl & 15;
            int c = ch ^ (r & 7);
            gload_lds16(&A[(size_t)(i0t + r) * CHH + c * 8], &th[sl * 8]);
        }
        __syncthreads();
#pragma unroll
        for (int s = 0; s < 4; ++s) {
            int irow = s * 16 + m;
            f32x4 acc = {0.f, 0.f, 0.f, 0.f};
#pragma unroll
            for (int kc = 0; kc < 4; ++kc) {
                int ch = (kc * 4 + quad) ^ (irow & 7);
                bf16x8 af = *(const bf16x8*)&th[irow * 128 + ch * 8];
                acc = __builtin_amdgcn_mfma_f32_16x16x32_bf16(af, bfr[kc], acc, 0, 0, 0);
            }
#pragma unroll
            for (int r = 0; r < 4; ++r)
                csum += __expf(acc[r] - KSHIFT);
        }
    }
    csum += __shfl_xor(csum, 16, 64);
    csum += __shfl_xor(csum, 32, 64);
    if (lane < 16)
        Lpart[((size_t)iq * BB + b) * NN + u] = csum;
}

// ---------------------------------------------------------------------------
// Kernel 6: LL[b][u] = K + log(sum of 4 i-quarter partials)
// ---------------------------------------------------------------------------
__global__ void lmerge_kernel(const float* __restrict__ Lpart, float* __restrict__ LL) {
    int idx = blockIdx.x * 256 + threadIdx.x;
    int b = idx >> 12, u = idx & 4095;
    float s = 0.f;
#pragma unroll
    for (int c = 0; c < 4; ++c)
        s += Lpart[((size_t)c * BB + b) * NN + u];
    LL[idx] = logf(s) + KSHIFT;
}

// ---------------------------------------------------------------------------
// Kernel 7 (pass B): Y = P @ X3. ROUND 9: u-split x2 — each block covers a
// 2048-u chunk, writing a bf16 partial-Y (Yp0/Yp1 alias dead T2b/T3b).
// Grid 1024 -> 4 blocks/CU (LDS 37.4 KB each) -> 2 waves/SIMD (was 1).
// Tile staging + swizzle structure proven round 8.
// ---------------------------------------------------------------------------
__launch_bounds__(128)
__global__ void attn_mfma_kernel(const unsigned short* __restrict__ T1b,
                                 const unsigned short* __restrict__ T2t,
                                 const unsigned short* __restrict__ X3t,
                                 const float* __restrict__ LL,
                                 unsigned short* __restrict__ Yp0,
                                 unsigned short* __restrict__ Yp1) {
    int blk = blockIdx.x;
    int b = (blk & 7) >> 1;
    int rest = (blk >> 3) * 2 + (blk & 1);   // 0..255 = it*2 + uc
    int it = rest >> 1, uc = rest & 1;
    int i0 = it * 32;
    unsigned short* Yp = uc ? Yp1 : Yp0;
    int flat = threadIdx.x;                   // 0..127
    int w = flat >> 6, lane = flat & 63, m = lane & 15, quad = lane >> 4;
    const unsigned short* A  = T1b + (size_t)b * CHH * NN;
    const unsigned short* Bt = T2t + (size_t)b * CHH * NN;
    const unsigned short* X3 = X3t + (size_t)b * CHH * NN;
    const float* LLb = LL + (size_t)b * NN;

    __shared__ unsigned short bt[64 * 128];   // phi^T tile, swizzled [u][chunk']
    __shared__ unsigned short x3[128 * 64];   // X3 tile, swizzled [j][chunk']
    __shared__ unsigned short pT[2][16][72];  // wave-private P tiles

    int iw = i0 + w * 16;
    bf16x8 ath[4];
#pragma unroll
    for (int kc = 0; kc < 4; ++kc)
        ath[kc] = ldb8(&A[(size_t)(iw + m) * CHH + kc * 32 + quad * 8]);
    f32x4 yacc[8];
#pragma unroll
    for (int js = 0; js < 8; ++js) yacc[js] = (f32x4){0.f, 0.f, 0.f, 0.f};

    int ubeg = uc * 2048, uend = ubeg + 2048;
    for (int u0 = ubeg; u0 < uend; u0 += 64) {
        __syncthreads();
#pragma unroll
        for (int i = 0; i < 8; ++i) {         // stage Bt tile (16 KB)
            int sl = i * 128 + flat;
            int u = sl >> 4, ch = sl & 15;
            int c = ch ^ (u & 7);
            gload_lds16(&Bt[(size_t)(u0 + u) * CHH + c * 8], &bt[sl * 8]);
        }
#pragma unroll
        for (int i = 0; i < 8; ++i) {         // stage X3 tile (16 KB)
            int sl = i * 128 + flat;
            int j = sl >> 3, ch = sl & 7;
            int c = ch ^ (j & 7);
            gload_lds16(&X3[(size_t)j * NN + u0 + c * 8], &x3[sl * 8]);
        }
        __syncthreads();
        // ---- S phase: S(16i x 64u), exp, P -> wave-private LDS ----
#pragma unroll
        for (int s = 0; s < 4; ++s) {
            int u = s * 16 + m;
            f32x4 acc = {0.f, 0.f, 0.f, 0.f};
#pragma unroll
            for (int kc = 0; kc < 4; ++kc) {
                int ch = (kc * 4 + quad) ^ (u & 7);
                bf16x8 bf = *(const bf16x8*)&bt[u * 128 + ch * 8];
                acc = __builtin_amdgcn_mfma_f32_16x16x32_bf16(ath[kc], bf, acc, 0, 0, 0);
            }
            float ll = LLb[u0 + u];
#pragma unroll
            for (int r = 0; r < 4; ++r)
                pT[w][quad * 4 + r][s * 16 + m] = f2bf(__expf(acc[r] - ll));
        }
        // ---- PV phase: Y(16i x 128j) += P @ X3 ----
        bf16x8 pa0 = *(const bf16x8*)&pT[w][m][quad * 8];
        bf16x8 pa1 = *(const bf16x8*)&pT[w][m][32 + quad * 8];
#pragma unroll
        for (int js = 0; js < 8; ++js) {
            int j = js * 16 + m;
            int ch0 = quad ^ (j & 7);
            int ch1 = (4 + quad) ^ (j & 7);
            bf16x8 xb0 = *(const bf16x8*)&x3[j * 64 + ch0 * 8];
            bf16x8 xb1 = *(const bf16x8*)&x3[j * 64 + ch1 * 8];
            yacc[js] = __builtin_amdgcn_mfma_f32_16x16x32_bf16(pa0, xb0, yacc[js], 0, 0, 0);
            yacc[js] = __builtin_amdgcn_mfma_f32_16x16x32_bf16(pa1, xb1, yacc[js], 0, 0, 0);
        }
    }
#pragma unroll
    for (int js = 0; js < 8; ++js)
#pragma unroll
        for (int r = 0; r < 4; ++r)
            Yp[((size_t)b * NN + iw + quad * 4 + r) * CHH + js * 16 + m] = f2bf(yacc[js][r]);
}

// ---------------------------------------------------------------------------
// Kernel 8: out = x + out_w @ (Yp0+Yp1)^T + out_b via MFMA.
// Merges the two u-split partials inside the fp32 MFMA accumulator
// (OW @ (Y0+Y1)^T = OW@Y0^T + OW@Y1^T).
// ---------------------------------------------------------------------------
template <typename T>
__device__ __forceinline__ void outconv_body(const T* __restrict__ x,
                                             const unsigned short* __restrict__ Yp0,
                                             const unsigned short* __restrict__ Yp1,
                                             const unsigned short* __restrict__ OWb,
                                             const float* __restrict__ OBf,
                                             T* __restrict__ out) {
    int b = blockIdx.y;
    int p0 = blockIdx.x * 16;
    int flat = threadIdx.x;
    int w = flat >> 6, lane = flat & 63, m = lane & 15, quad = lane >> 4;
    const unsigned short* yrow0 = Yp0 + ((size_t)b * NN + p0 + m) * CHH;
    const unsigned short* yrow1 = Yp1 + ((size_t)b * NN + p0 + m) * CHH;
    bf16x8 yf0[4], yf1[4];
#pragma unroll
    for (int kc = 0; kc < 4; ++kc) {
        yf0[kc] = ldb8(&yrow0[kc * 32 + quad * 8]);
        yf1[kc] = ldb8(&yrow1[kc * 32 + quad * 8]);
    }
#pragma unroll
    for (int q = 0; q < 4; ++q) {
        int o0 = (w * 4 + q) * 16;
        const unsigned short* wrow = OWb + (size_t)(o0 + m) * CHH;
        f32x4 acc = {0.f, 0.f, 0.f, 0.f};
#pragma unroll
        for (int kc = 0; kc < 4; ++kc) {
            bf16x8 aw = ldb8(&wrow[kc * 32 + quad * 8]);
            acc = __builtin_amdgcn_mfma_f32_16x16x32_bf16(aw, yf0[kc], acc, 0, 0, 0);
            acc = __builtin_amdgcn_mfma_f32_16x16x32_bf16(aw, yf1[kc], acc, 0, 0, 0);
        }
#pragma unroll
        for (int r = 0; r < 4; ++r) {
            int co = o0 + quad * 4 + r;
            size_t oi = ((size_t)b * CC + co) * NN + p0 + m;
            st_f(&out[oi], acc[r] + OBf[co] + to_f(x[oi]));
        }
    }
}

__launch_bounds__(256)
__global__ void outconv_mfma_kernel(const void* x,
                                    const unsigned short* __restrict__ Yp0,
                                    const unsigned short* __restrict__ Yp1,
                                    const unsigned short* __restrict__ OWb,
                                    const float* __restrict__ OBf,
                                    const int* __restrict__ flag, void* out) {
    if (*flag)
        outconv_body<float>((const float*)x, Yp0, Yp1, OWb, OBf, (float*)out);
    else
        outconv_body<__hip_bfloat16>((const __hip_bfloat16*)x, Yp0, Yp1, OWb, OBf,
                                     (__hip_bfloat16*)out);
}

extern "C" void kernel_launch(void* const* d_in, const int* in_sizes, int n_in,
                              void* d_out, int out_size, void* d_ws, size_t ws_size,
                              hipStream_t stream) {
    const void* x  = d_in[0];
    const void* tw = d_in[1];
    const void* tb = d_in[2];
    const void* fw = d_in[3];
    const void* fb = d_in[4];
    const void* gw = d_in[5];
    const void* gb = d_in[6];
    const void* ow = d_in[7];
    const void* ob = d_in[8];

    // Workspace (~22 MB) with aliasing: partial-Y buffers alias T2b/T3b,
    // which are dead once the T2t/X3t transposes have run.
    const size_t TE = (size_t)BB * CHH * NN;        // 2,097,152
    unsigned short* T1b = (unsigned short*)d_ws;
    unsigned short* T2b = T1b + TE;
    unsigned short* T3b = T2b + TE;
    unsigned short* xt  = T3b + TE;                 // 2*TE shorts
    unsigned short* T2t = xt;                       // alias: low half of xt (dead after conv3)
    unsigned short* X3t = xt + TE;                  // alias: high half of xt
    unsigned short* Yp0 = T2b;                      // alias: dead during attn
    unsigned short* Yp1 = T3b;                      // alias: dead during attn
    unsigned short* Wb  = xt + 2 * TE;              // 98304 shorts
    unsigned short* OWb = Wb + 98304;               // 32768 shorts
    float* Bf    = (float*)(OWb + 32768);           // 384
    float* OBf   = Bf + 384;                        // 256
    float* Lpart = OBf + 256;                       // 4 * BB * NN = 65536
    float* LLb   = Lpart + 65536;                   // 16384
    int*   Flag  = (int*)(LLb + 16384);

    detect_kernel<<<1, 64, 0, stream>>>(tb, Flag);
    prep_kernel<<<dim3(515), 256, 0, stream>>>(tw, fw, gw, ow, tb, fb, gb, ob,
                                               Flag, Wb, OWb, Bf, OBf);
    xtrans_kernel<<<dim3(NN / 64, CC / 64, BB), 256, 0, stream>>>(x, Flag, xt);
    conv3_mfma_kernel<<<dim3(NN / 16, BB), 256, 0, stream>>>(xt, Wb, Bf, T1b, T2b, T3b);
    transpose_kernel<<<dim3(NN / 64, CHH / 64, BB), 256, 0, stream>>>(T2b, T2t, CHH, NN);
    transpose_kernel<<<dim3(CHH / 64, NN / 64, BB), 256, 0, stream>>>(T3b, X3t, NN, CHH);
    stats_mfma_kernel<<<dim3(1024), 256, 0, stream>>>(T1b, T2t, Lpart);
    lmerge_kernel<<<dim3(BB * NN / 256), 256, 0, stream>>>(Lpart, LLb);
    attn_mfma_kernel<<<dim3(1024), 128, 0, stream>>>(T1b, T2t, X3t, LLb, Yp0, Yp1);
    outconv_mfma_kernel<<<dim3(NN / 16, BB), 256, 0, stream>>>(x, Yp0, Yp1, OWb, OBf, Flag, d_out);
}

// Round 10
// 231.595 us; speedup vs baseline: 2.1607x; 1.0579x over previous
//
#include <hip/hip_runtime.h>
#include <hip/hip_bf16.h>

#define BB 4
#define CC 256
#define CHH 128
#define NN 4096
#define KSHIFT 12.0f

typedef __attribute__((ext_vector_type(8))) short bf16x8;
typedef __attribute__((ext_vector_type(4))) float f32x4;

__device__ __forceinline__ float to_f(float v) { return v; }
__device__ __forceinline__ float to_f(__hip_bfloat16 v) { return __bfloat162float(v); }
__device__ __forceinline__ void st_f(float* p, float v) { *p = v; }
__device__ __forceinline__ void st_f(__hip_bfloat16* p, float v) { *p = __float2bfloat16(v); }
__device__ __forceinline__ unsigned short f2bf(float f) {
    __hip_bfloat16 h = __float2bfloat16(f);
    unsigned short u;
    __builtin_memcpy(&u, &h, 2);
    return u;
}
__device__ __forceinline__ bf16x8 ldb8(const unsigned short* p) { return *(const bf16x8*)p; }

// async global->LDS, 16 B per lane. LDS dest = wave-uniform base + lane*16.
__device__ __forceinline__ void gload_lds16(const unsigned short* g, unsigned short* l) {
    __builtin_amdgcn_global_load_lds(
        (const __attribute__((address_space(1))) unsigned int*)g,
        (__attribute__((address_space(3))) unsigned int*)l, 16, 0, 0);
}

// ---------------------------------------------------------------------------
// Kernel 0: wire-dtype detection (proven rounds 3-9 — keep).
// ---------------------------------------------------------------------------
__global__ void detect_kernel(const void* __restrict__ tb, int* __restrict__ flag) {
    if (threadIdx.x == 0) {
        const __hip_bfloat16* p = (const __hip_bfloat16*)tb;
        int big = 0, zeros = 0;
        for (int i = 0; i < 128; ++i) {
            float v = __bfloat162float(p[i]);
            if (!(fabsf(v) <= 0.5f)) big = 1;
            if ((i & 1) == 0 && v == 0.0f) zeros++;
        }
        *flag = (big || zeros >= 32) ? 1 : 0;
    }
}

// ---------------------------------------------------------------------------
// Kernel 1: convert all weights/biases once (proven round 6).
// ---------------------------------------------------------------------------
template <typename T>
__device__ __forceinline__ void prep_body(const T* tw, const T* fw, const T* gw, const T* ow,
                                          const T* tb2, const T* fb, const T* gb, const T* ob,
                                          unsigned short* Wb, unsigned short* OWb,
                                          float* Bf, float* OBf) {
    int idx = blockIdx.x * 256 + threadIdx.x;
    if (idx < 98304) {
        int cv = idx >> 15, rem = idx & 32767;
        const T* src = cv == 0 ? tw : (cv == 1 ? fw : gw);
        Wb[idx] = f2bf(to_f(src[rem]));
    } else if (idx < 131072) {
        OWb[idx - 98304] = f2bf(to_f(ow[idx - 98304]));
    } else if (idx < 131456) {
        int r = idx - 131072;
        int cv = r >> 7, j = r & 127;
        const T* src = cv == 0 ? tb2 : (cv == 1 ? fb : gb);
        Bf[r] = to_f(src[j]);
    } else if (idx < 131712) {
        OBf[idx - 131456] = to_f(ob[idx - 131456]);
    }
}

__global__ void prep_kernel(const void* tw, const void* fw, const void* gw, const void* ow,
                            const void* tb2, const void* fb, const void* gb, const void* ob,
                            const int* __restrict__ flag,
                            unsigned short* Wb, unsigned short* OWb, float* Bf, float* OBf) {
    if (*flag)
        prep_body<float>((const float*)tw, (const float*)fw, (const float*)gw, (const float*)ow,
                         (const float*)tb2, (const float*)fb, (const float*)gb, (const float*)ob,
                         Wb, OWb, Bf, OBf);
    else
        prep_body<__hip_bfloat16>((const __hip_bfloat16*)tw, (const __hip_bfloat16*)fw,
                                  (const __hip_bfloat16*)gw, (const __hip_bfloat16*)ow,
                                  (const __hip_bfloat16*)tb2, (const __hip_bfloat16*)fb,
                                  (const __hip_bfloat16*)gb, (const __hip_bfloat16*)ob,
                                  Wb, OWb, Bf, OBf);
}

// ---------------------------------------------------------------------------
// Kernel 2: xt[b][p][c] = bf16(x[b][c][p]) (proven round 6).
// ---------------------------------------------------------------------------
template <typename T>
__device__ __forceinline__ void xtrans_body(const T* __restrict__ x, unsigned short* __restrict__ xt) {
    int b = blockIdx.z;
    const T* in = x + (size_t)b * CC * NN;
    unsigned short* out = xt + (size_t)b * NN * CC;
    int p0 = blockIdx.x * 64, c0 = blockIdx.y * 64;
    __shared__ unsigned short t[64][68];
    int flat = threadIdx.x;
#pragma unroll
    for (int tt = 0; tt < 16; ++tt) {
        int id = flat + tt * 256;
        int rr = id >> 6, cc = id & 63;
        t[cc][rr] = f2bf(to_f(in[(size_t)(c0 + rr) * NN + p0 + cc]));
    }
    __syncthreads();
#pragma unroll
    for (int tt = 0; tt < 16; ++tt) {
        int id = flat + tt * 256;
        int pp = id >> 6, jj = id & 63;
        out[(size_t)(p0 + pp) * CC + c0 + jj] = t[pp][jj];
    }
}

__launch_bounds__(256)
__global__ void xtrans_kernel(const void* x, const int* __restrict__ flag,
                              unsigned short* __restrict__ xt) {
    if (*flag) xtrans_body<float>((const float*)x, xt);
    else       xtrans_body<__hip_bfloat16>((const __hip_bfloat16*)x, xt);
}

// ---------------------------------------------------------------------------
// Kernel 3: three 1x1 convs via MFMA (proven round 6).
// ---------------------------------------------------------------------------
__launch_bounds__(256)
__global__ void conv3_mfma_kernel(const unsigned short* __restrict__ xt,
                                  const unsigned short* __restrict__ Wb,
                                  const float* __restrict__ Bf,
                                  unsigned short* __restrict__ T1b,
                                  unsigned short* __restrict__ T2b,
                                  unsigned short* __restrict__ T3b) {
    int b = blockIdx.y;
    int p0 = blockIdx.x * 16;
    int flat = threadIdx.x;
    int w = flat >> 6, lane = flat & 63, m = lane & 15, quad = lane >> 4;
    const unsigned short* xrow = xt + ((size_t)b * NN + p0 + m) * CC;
    bf16x8 xf[8];
#pragma unroll
    for (int kc = 0; kc < 8; ++kc)
        xf[kc] = ldb8(&xrow[kc * 32 + quad * 8]);
    unsigned short* outs[3] = {T1b + (size_t)b * CHH * NN,
                               T2b + (size_t)b * CHH * NN,
                               T3b + (size_t)b * CHH * NN};
#pragma unroll
    for (int q = 0; q < 6; ++q) {
        int t = w * 6 + q;
        int cv = t >> 3, ot = t & 7;
        int o0 = ot * 16;
        const unsigned short* wrow = Wb + ((size_t)cv * CHH + o0 + m) * CC;
        f32x4 acc = {0.f, 0.f, 0.f, 0.f};
#pragma unroll
        for (int kc = 0; kc < 8; ++kc) {
            bf16x8 wf = ldb8(&wrow[kc * 32 + quad * 8]);
            acc = __builtin_amdgcn_mfma_f32_16x16x32_bf16(wf, xf[kc], acc, 0, 0, 0);
        }
#pragma unroll
        for (int r = 0; r < 4; ++r) {
            int o = o0 + quad * 4 + r;
            outs[cv][(size_t)o * NN + p0 + m] = f2bf(acc[r] + Bf[cv * CHH + o]);
        }
    }
}

// ---------------------------------------------------------------------------
// Kernel 4: generic bf16 tiled transpose (proven).
// ---------------------------------------------------------------------------
__launch_bounds__(256)
__global__ void transpose_kernel(const unsigned short* __restrict__ in,
                                 unsigned short* __restrict__ out, int R, int C) {
    int bz = blockIdx.z;
    in  += (size_t)bz * R * C;
    out += (size_t)bz * R * C;
    int c0 = blockIdx.x * 64, r0 = blockIdx.y * 64;
    __shared__ unsigned short t[64][68];
    int flat = threadIdx.x;
#pragma unroll
    for (int tt = 0; tt < 16; ++tt) {
        int id = flat + tt * 256;
        int r = id >> 6, c = id & 63;
        t[c][r] = in[(size_t)(r0 + r) * C + c0 + c];
    }
    __syncthreads();
#pragma unroll
    for (int tt = 0; tt < 16; ++tt) {
        int id = flat + tt * 256;
        int c = id >> 6, r = id & 63;
        out[(size_t)(c0 + c) * R + r0 + r] = t[c][r];
    }
}

// ---------------------------------------------------------------------------
// Kernel 5 (pass A): colsum exp(S-K). ROUND 10: each wave covers 32 u
// (bfr[2][4] register-resident) -> 32 MFMAs per staged 16 KB theta tile
// (2x intensity), theta traffic 256 -> 128 MB. Grid 1024 = 4 blocks/CU
// = 4 waves/SIMD. Staging/swizzle machinery proven rounds 8-9.
// ---------------------------------------------------------------------------
__launch_bounds__(256)
__global__ void stats_mfma_kernel(const unsigned short* __restrict__ T1b,
                                  const unsigned short* __restrict__ T2t,
                                  float* __restrict__ Lpart) {
    int blk = blockIdx.x;
    int b = (blk & 7) >> 1;
    int rest = (blk >> 3) * 2 + (blk & 1);   // 0..255 = strip*8 + iq
    int strip = rest >> 3, iq = rest & 7;
    int ibase = iq * 512;
    int flat = threadIdx.x;
    int w = flat >> 6, lane = flat & 63, m = lane & 15, quad = lane >> 4;
    const unsigned short* A  = T1b + (size_t)b * CHH * NN;
    const unsigned short* Bt = T2t + (size_t)b * CHH * NN;
    __shared__ unsigned short th[64 * 128];   // theta tile, swizzled [i][chunk']

    int u0w = strip * 128 + w * 32;           // this wave's 32-u window
    bf16x8 bfr[2][4];
#pragma unroll
    for (int g = 0; g < 2; ++g)
#pragma unroll
        for (int kc = 0; kc < 4; ++kc)
            bfr[g][kc] = ldb8(&Bt[(size_t)(u0w + g * 16 + m) * CHH + kc * 32 + quad * 8]);

    float csum[2] = {0.f, 0.f};
    for (int t = 0; t < 8; ++t) {            // 8 i-tiles of 64 in this chunk
        int i0t = ibase + t * 64;
        __syncthreads();
#pragma unroll
        for (int i = 0; i < 4; ++i) {
            int sl = i * 256 + flat;
            int r = sl >> 4, ch = sl & 15;
            int c = ch ^ (r & 7);
            gload_lds16(&A[(size_t)(i0t + r) * CHH + c * 8], &th[sl * 8]);
        }
        __syncthreads();
#pragma unroll
        for (int s = 0; s < 4; ++s) {
            int irow = s * 16 + m;
            bf16x8 af[4];
#pragma unroll
            for (int kc = 0; kc < 4; ++kc) {
                int ch = (kc * 4 + quad) ^ (irow & 7);
                af[kc] = *(const bf16x8*)&th[irow * 128 + ch * 8];
            }
#pragma unroll
            for (int g = 0; g < 2; ++g) {
                f32x4 acc = {0.f, 0.f, 0.f, 0.f};
#pragma unroll
                for (int kc = 0; kc < 4; ++kc)
                    acc = __builtin_amdgcn_mfma_f32_16x16x32_bf16(af[kc], bfr[g][kc], acc, 0, 0, 0);
#pragma unroll
                for (int r = 0; r < 4; ++r)
                    csum[g] += __expf(acc[r] - KSHIFT);
            }
        }
    }
#pragma unroll
    for (int g = 0; g < 2; ++g) {
        csum[g] += __shfl_xor(csum[g], 16, 64);
        csum[g] += __shfl_xor(csum[g], 32, 64);
        if (lane < 16)
            Lpart[((size_t)iq * BB + b) * NN + u0w + g * 16 + m] = csum[g];
    }
}

// ---------------------------------------------------------------------------
// Kernel 6: LL[b][u] = K + log(sum of 8 i-chunk partials)
// ---------------------------------------------------------------------------
__global__ void lmerge_kernel(const float* __restrict__ Lpart, float* __restrict__ LL) {
    int idx = blockIdx.x * 256 + threadIdx.x;
    int b = idx >> 12, u = idx & 4095;
    float s = 0.f;
#pragma unroll
    for (int c = 0; c < 8; ++c)
        s += Lpart[((size_t)c * BB + b) * NN + u];
    LL[idx] = logf(s) + KSHIFT;
}

// ---------------------------------------------------------------------------
// Kernel 7 (pass B): Y = P @ X3. ROUND 10: 4-wave blocks, i-tile 64 — the
// same 32 KB staged tile now feeds 128 MFMAs (2x intensity, traffic -> 512 MB);
// u-split x4 with 4 bf16 partial-Y buffers. pT packed to 32-u halves
// ([4][16][40]) so LDS = 37.9 KB -> 4 blocks/CU = 4 waves/SIMD (was 2).
// Staging/swizzle/C->A-hop machinery proven rounds 8-9.
// ---------------------------------------------------------------------------
__launch_bounds__(256)
__global__ void attn_mfma_kernel(const unsigned short* __restrict__ T1b,
                                 const unsigned short* __restrict__ T2t,
                                 const unsigned short* __restrict__ X3t,
                                 const float* __restrict__ LL,
                                 unsigned short* __restrict__ Yp0,
                                 unsigned short* __restrict__ Yp1,
                                 unsigned short* __restrict__ Yp2,
                                 unsigned short* __restrict__ Yp3) {
    int blk = blockIdx.x;
    int b = (blk & 7) >> 1;
    int rest = (blk >> 3) * 2 + (blk & 1);   // 0..255 = it*4 + uc
    int it = rest >> 2, uc = rest & 3;
    int i0 = it * 64;
    unsigned short* Yp = uc == 0 ? Yp0 : (uc == 1 ? Yp1 : (uc == 2 ? Yp2 : Yp3));
    int flat = threadIdx.x;                   // 0..255
    int w = flat >> 6, lane = flat & 63, m = lane & 15, quad = lane >> 4;
    const unsigned short* A  = T1b + (size_t)b * CHH * NN;
    const unsigned short* Bt = T2t + (size_t)b * CHH * NN;
    const unsigned short* X3 = X3t + (size_t)b * CHH * NN;
    const float* LLb = LL + (size_t)b * NN;

    __shared__ unsigned short bt[64 * 128];   // phi^T tile, swizzled [u][chunk']
    __shared__ unsigned short x3[128 * 64];   // X3 tile, swizzled [j][chunk']
    __shared__ unsigned short pT[4][16][40];  // wave-private P half-tiles (32 u)

    int iw = i0 + w * 16;
    bf16x8 ath[4];
#pragma unroll
    for (int kc = 0; kc < 4; ++kc)
        ath[kc] = ldb8(&A[(size_t)(iw + m) * CHH + kc * 32 + quad * 8]);
    f32x4 yacc[8];
#pragma unroll
    for (int js = 0; js < 8; ++js) yacc[js] = (f32x4){0.f, 0.f, 0.f, 0.f};

    int ubeg = uc * 1024, uend = ubeg + 1024;
    for (int u0 = ubeg; u0 < uend; u0 += 64) {
        __syncthreads();                      // prev tile reads done
#pragma unroll
        for (int i = 0; i < 4; ++i) {         // stage Bt tile (16 KB)
            int sl = i * 256 + flat;
            int u = sl >> 4, ch = sl & 15;
            int c = ch ^ (u & 7);
            gload_lds16(&Bt[(size_t)(u0 + u) * CHH + c * 8], &bt[sl * 8]);
        }
#pragma unroll
        for (int i = 0; i < 4; ++i) {         // stage X3 tile (16 KB)
            int sl = i * 256 + flat;
            int j = sl >> 3, ch = sl & 7;
            int c = ch ^ (j & 7);
            gload_lds16(&X3[(size_t)j * NN + u0 + c * 8], &x3[sl * 8]);
        }
        __syncthreads();                      // staging visible
#pragma unroll
        for (int h = 0; h < 2; ++h) {         // two 32-u halves
            // ---- S phase: S(16i x 32u), exp, P -> wave-private LDS ----
#pragma unroll
            for (int su = 0; su < 2; ++su) {
                int u = (h * 2 + su) * 16 + m;
                f32x4 acc = {0.f, 0.f, 0.f, 0.f};
#pragma unroll
                for (int kc = 0; kc < 4; ++kc) {
                    int ch = (kc * 4 + quad) ^ (u & 7);
                    bf16x8 bf = *(const bf16x8*)&bt[u * 128 + ch * 8];
                    acc = __builtin_amdgcn_mfma_f32_16x16x32_bf16(ath[kc], bf, acc, 0, 0, 0);
                }
                float ll = LLb[u0 + u];
#pragma unroll
                for (int r = 0; r < 4; ++r)
                    pT[w][quad * 4 + r][su * 16 + m] = f2bf(__expf(acc[r] - ll));
            }
            // ---- PV phase: Y(16i x 128j) += P_half @ X3_half ----
            bf16x8 pa = *(const bf16x8*)&pT[w][m][quad * 8];
#pragma unroll
            for (int js = 0; js < 8; ++js) {
                int j = js * 16 + m;
                int ch = (h * 4 + quad) ^ (j & 7);
                bf16x8 xb = *(const bf16x8*)&x3[j * 64 + ch * 8];
                yacc[js] = __builtin_amdgcn_mfma_f32_16x16x32_bf16(pa, xb, yacc[js], 0, 0, 0);
            }
        }
    }
#pragma unroll
    for (int js = 0; js < 8; ++js)
#pragma unroll
        for (int r = 0; r < 4; ++r)
            Yp[((size_t)b * NN + iw + quad * 4 + r) * CHH + js * 16 + m] = f2bf(yacc[js][r]);
}

// ---------------------------------------------------------------------------
// Kernel 8: out = x + out_w @ (Yp0+Yp1+Yp2+Yp3)^T + out_b via MFMA.
// Partials merged inside the fp32 MFMA accumulator (linear in Y).
// ---------------------------------------------------------------------------
template <typename T>
__device__ __forceinline__ void outconv_body(const T* __restrict__ x,
                                             const unsigned short* __restrict__ Yp0,
                                             const unsigned short* __restrict__ Yp1,
                                             const unsigned short* __restrict__ Yp2,
                                             const unsigned short* __restrict__ Yp3,
                                             const unsigned short* __restrict__ OWb,
                                             const float* __restrict__ OBf,
                                             T* __restrict__ out) {
    int b = blockIdx.y;
    int p0 = blockIdx.x * 16;
    int flat = threadIdx.x;
    int w = flat >> 6, lane = flat & 63, m = lane & 15, quad = lane >> 4;
    size_t yoff = ((size_t)b * NN + p0 + m) * CHH;
    const unsigned short* yrows[4] = {Yp0 + yoff, Yp1 + yoff, Yp2 + yoff, Yp3 + yoff};
    bf16x8 yf[4][4];
#pragma unroll
    for (int pz = 0; pz < 4; ++pz)
#pragma unroll
        for (int kc = 0; kc < 4; ++kc)
            yf[pz][kc] = ldb8(&yrows[pz][kc * 32 + quad * 8]);
#pragma unroll
    for (int q = 0; q < 4; ++q) {
        int o0 = (w * 4 + q) * 16;
        const unsigned short* wrow = OWb + (size_t)(o0 + m) * CHH;
        f32x4 acc = {0.f, 0.f, 0.f, 0.f};
#pragma unroll
        for (int kc = 0; kc < 4; ++kc) {
            bf16x8 aw = ldb8(&wrow[kc * 32 + quad * 8]);
#pragma unroll
            for (int pz = 0; pz < 4; ++pz)
                acc = __builtin_amdgcn_mfma_f32_16x16x32_bf16(aw, yf[pz][kc], acc, 0, 0, 0);
        }
#pragma unroll
        for (int r = 0; r < 4; ++r) {
            int co = o0 + quad * 4 + r;
            size_t oi = ((size_t)b * CC + co) * NN + p0 + m;
            st_f(&out[oi], acc[r] + OBf[co] + to_f(x[oi]));
        }
    }
}

__launch_bounds__(256)
__global__ void outconv_mfma_kernel(const void* x,
                                    const unsigned short* __restrict__ Yp0,
                                    const unsigned short* __restrict__ Yp1,
                                    const unsigned short* __restrict__ Yp2,
                                    const unsigned short* __restrict__ Yp3,
                                    const unsigned short* __restrict__ OWb,
                                    const float* __restrict__ OBf,
                                    const int* __restrict__ flag, void* out) {
    if (*flag)
        outconv_body<float>((const float*)x, Yp0, Yp1, Yp2, Yp3, OWb, OBf, (float*)out);
    else
        outconv_body<__hip_bfloat16>((const __hip_bfloat16*)x, Yp0, Yp1, Yp2, Yp3, OWb, OBf,
                                     (__hip_bfloat16*)out);
}

extern "C" void kernel_launch(void* const* d_in, const int* in_sizes, int n_in,
                              void* d_out, int out_size, void* d_ws, size_t ws_size,
                              hipStream_t stream) {
    const void* x  = d_in[0];
    const void* tw = d_in[1];
    const void* tb = d_in[2];
    const void* fw = d_in[3];
    const void* fb = d_in[4];
    const void* gw = d_in[5];
    const void* gb = d_in[6];
    const void* ow = d_in[7];
    const void* ob = d_in[8];

    // Workspace (~30 MB): Yp0/Yp1 alias dead T2b/T3b; Yp2/Yp3 fresh.
    const size_t TE = (size_t)BB * CHH * NN;        // 2,097,152
    unsigned short* T1b = (unsigned short*)d_ws;
    unsigned short* T2b = T1b + TE;
    unsigned short* T3b = T2b + TE;
    unsigned short* xt  = T3b + TE;                 // 2*TE shorts
    unsigned short* T2t = xt;                       // alias: low half of xt (dead after conv3)
    unsigned short* X3t = xt + TE;                  // alias: high half of xt
    unsigned short* Yp0 = T2b;                      // alias: dead during attn
    unsigned short* Yp1 = T3b;                      // alias: dead during attn
    unsigned short* Yp2 = xt + 2 * TE;              // fresh
    unsigned short* Yp3 = Yp2 + TE;                 // fresh
    unsigned short* Wb  = Yp3 + TE;                 // 98304 shorts
    unsigned short* OWb = Wb + 98304;               // 32768 shorts
    float* Bf    = (float*)(OWb + 32768);           // 384
    float* OBf   = Bf + 384;                        // 256
    float* Lpart = OBf + 256;                       // 8 * BB * NN = 131072
    float* LLb   = Lpart + 131072;                  // 16384
    int*   Flag  = (int*)(LLb + 16384);

    detect_kernel<<<1, 64, 0, stream>>>(tb, Flag);
    prep_kernel<<<dim3(515), 256, 0, stream>>>(tw, fw, gw, ow, tb, fb, gb, ob,
                                               Flag, Wb, OWb, Bf, OBf);
    xtrans_kernel<<<dim3(NN / 64, CC / 64, BB), 256, 0, stream>>>(x, Flag, xt);
    conv3_mfma_kernel<<<dim3(NN / 16, BB), 256, 0, stream>>>(xt, Wb, Bf, T1b, T2b, T3b);
    transpose_kernel<<<dim3(NN / 64, CHH / 64, BB), 256, 0, stream>>>(T2b, T2t, CHH, NN);
    transpose_kernel<<<dim3(CHH / 64, NN / 64, BB), 256, 0, stream>>>(T3b, X3t, NN, CHH);
    stats_mfma_kernel<<<dim3(1024), 256, 0, stream>>>(T1b, T2t, Lpart);
    lmerge_kernel<<<dim3(BB * NN / 256), 256, 0, stream>>>(Lpart, LLb);
    attn_mfma_kernel<<<dim3(1024), 256, 0, stream>>>(T1b, T2t, X3t, LLb, Yp0, Yp1, Yp2, Yp3);
    outconv_mfma_kernel<<<dim3(NN / 16, BB), 256, 0, stream>>>(x, Yp0, Yp1, Yp2, Yp3,
                                                               OWb, OBf, Flag, d_out);
}

// Round 12
// 213.883 us; speedup vs baseline: 2.3396x; 1.0828x over previous
//
#include <hip/hip_runtime.h>
#include <hip/hip_bf16.h>

#define BB 4
#define CC 256
#define CHH 128
#define NN 4096
#define KSHIFT 12.0f

typedef __attribute__((ext_vector_type(8))) short bf16x8;
typedef __attribute__((ext_vector_type(4))) float f32x4;

__device__ __forceinline__ float to_f(float v) { return v; }
__device__ __forceinline__ float to_f(__hip_bfloat16 v) { return __bfloat162float(v); }
__device__ __forceinline__ void st_f(float* p, float v) { *p = v; }
__device__ __forceinline__ void st_f(__hip_bfloat16* p, float v) { *p = __float2bfloat16(v); }
__device__ __forceinline__ unsigned short f2bf(float f) {
    __hip_bfloat16 h = __float2bfloat16(f);
    unsigned short u;
    __builtin_memcpy(&u, &h, 2);
    return u;
}
__device__ __forceinline__ bf16x8 ldb8(const unsigned short* p) { return *(const bf16x8*)p; }

// async global->LDS, 16 B per lane. LDS dest = wave-uniform base + lane*16.
__device__ __forceinline__ void gload_lds16(const unsigned short* g, unsigned short* l) {
    __builtin_amdgcn_global_load_lds(
        (const __attribute__((address_space(1))) unsigned int*)g,
        (__attribute__((address_space(3))) unsigned int*)l, 16, 0, 0);
}

// ---------------------------------------------------------------------------
// Kernel 0: wire-dtype detection (proven rounds 3-10 — keep).
// ---------------------------------------------------------------------------
__global__ void detect_kernel(const void* __restrict__ tb, int* __restrict__ flag) {
    if (threadIdx.x == 0) {
        const __hip_bfloat16* p = (const __hip_bfloat16*)tb;
        int big = 0, zeros = 0;
        for (int i = 0; i < 128; ++i) {
            float v = __bfloat162float(p[i]);
            if (!(fabsf(v) <= 0.5f)) big = 1;
            if ((i & 1) == 0 && v == 0.0f) zeros++;
        }
        *flag = (big || zeros >= 32) ? 1 : 0;
    }
}

// ---------------------------------------------------------------------------
// Kernel 1: convert all weights/biases once (proven round 6).
// ---------------------------------------------------------------------------
template <typename T>
__device__ __forceinline__ void prep_body(const T* tw, const T* fw, const T* gw, const T* ow,
                                          const T* tb2, const T* fb, const T* gb, const T* ob,
                                          unsigned short* Wb, unsigned short* OWb,
                                          float* Bf, float* OBf) {
    int idx = blockIdx.x * 256 + threadIdx.x;
    if (idx < 98304) {
        int cv = idx >> 15, rem = idx & 32767;
        const T* src = cv == 0 ? tw : (cv == 1 ? fw : gw);
        Wb[idx] = f2bf(to_f(src[rem]));
    } else if (idx < 131072) {
        OWb[idx - 98304] = f2bf(to_f(ow[idx - 98304]));
    } else if (idx < 131456) {
        int r = idx - 131072;
        int cv = r >> 7, j = r & 127;
        const T* src = cv == 0 ? tb2 : (cv == 1 ? fb : gb);
        Bf[r] = to_f(src[j]);
    } else if (idx < 131712) {
        OBf[idx - 131456] = to_f(ob[idx - 131456]);
    }
}

__global__ void prep_kernel(const void* tw, const void* fw, const void* gw, const void* ow,
                            const void* tb2, const void* fb, const void* gb, const void* ob,
                            const int* __restrict__ flag,
                            unsigned short* Wb, unsigned short* OWb, float* Bf, float* OBf) {
    if (*flag)
        prep_body<float>((const float*)tw, (const float*)fw, (const float*)gw, (const float*)ow,
                         (const float*)tb2, (const float*)fb, (const float*)gb, (const float*)ob,
                         Wb, OWb, Bf, OBf);
    else
        prep_body<__hip_bfloat16>((const __hip_bfloat16*)tw, (const __hip_bfloat16*)fw,
                                  (const __hip_bfloat16*)gw, (const __hip_bfloat16*)ow,
                                  (const __hip_bfloat16*)tb2, (const __hip_bfloat16*)fb,
                                  (const __hip_bfloat16*)gb, (const __hip_bfloat16*)ob,
                                  Wb, OWb, Bf, OBf);
}

// ---------------------------------------------------------------------------
// Kernel 2: xt[b][p][c] = bf16(x[b][c][p]) (proven round 6).
// ---------------------------------------------------------------------------
template <typename T>
__device__ __forceinline__ void xtrans_body(const T* __restrict__ x, unsigned short* __restrict__ xt) {
    int b = blockIdx.z;
    const T* in = x + (size_t)b * CC * NN;
    unsigned short* out = xt + (size_t)b * NN * CC;
    int p0 = blockIdx.x * 64, c0 = blockIdx.y * 64;
    __shared__ unsigned short t[64][68];
    int flat = threadIdx.x;
#pragma unroll
    for (int tt = 0; tt < 16; ++tt) {
        int id = flat + tt * 256;
        int rr = id >> 6, cc = id & 63;
        t[cc][rr] = f2bf(to_f(in[(size_t)(c0 + rr) * NN + p0 + cc]));
    }
    __syncthreads();
#pragma unroll
    for (int tt = 0; tt < 16; ++tt) {
        int id = flat + tt * 256;
        int pp = id >> 6, jj = id & 63;
        out[(size_t)(p0 + pp) * CC + c0 + jj] = t[pp][jj];
    }
}

__launch_bounds__(256)
__global__ void xtrans_kernel(const void* x, const int* __restrict__ flag,
                              unsigned short* __restrict__ xt) {
    if (*flag) xtrans_body<float>((const float*)x, xt);
    else       xtrans_body<__hip_bfloat16>((const __hip_bfloat16*)x, xt);
}

// ---------------------------------------------------------------------------
// Kernel 3: three 1x1 convs via MFMA.
//   cv=0 (theta): natural (CH,N) store -> T1b (== (N,CH) view).
//   cv=1 (phi):   T2t[p*128+o] written directly via 16x16 in-wave shfl
//                 transpose (audited: lane l' pulls D[o0+(l'&3)*4+k][p0+l'>>2]).
//   cv=2 (g):     natural store -> T3b. X3t CANNOT be fused (its layout
//                 X3t[(p&127)*NN + o*32 + (p>>7)] is an image-scale scatter
//                 per conv tile — the round-11 fusion bug); standalone
//                 transpose reinstated below.
// ---------------------------------------------------------------------------
__launch_bounds__(256)
__global__ void conv3_mfma_kernel(const unsigned short* __restrict__ xt,
                                  const unsigned short* __restrict__ Wb,
                                  const float* __restrict__ Bf,
                                  unsigned short* __restrict__ T1b,
                                  unsigned short* __restrict__ T2t,
                                  unsigned short* __restrict__ T3b) {
    int b = blockIdx.y;
    int p0 = blockIdx.x * 16;
    int flat = threadIdx.x;
    int w = flat >> 6, lane = flat & 63, m = lane & 15, quad = lane >> 4;
    const unsigned short* xrow = xt + ((size_t)b * NN + p0 + m) * CC;
    bf16x8 xf[8];
#pragma unroll
    for (int kc = 0; kc < 8; ++kc)
        xf[kc] = ldb8(&xrow[kc * 32 + quad * 8]);
    unsigned short* t1  = T1b + (size_t)b * CHH * NN;
    unsigned short* t2t = T2t + (size_t)b * CHH * NN;   // [p][o], row stride 128
    unsigned short* t3  = T3b + (size_t)b * CHH * NN;   // natural (CH,N)
#pragma unroll
    for (int q = 0; q < 6; ++q) {
        int t = w * 6 + q;
        int cv = t >> 3, ot = t & 7;
        int o0 = ot * 16;
        const unsigned short* wrow = Wb + ((size_t)cv * CHH + o0 + m) * CC;
        f32x4 acc = {0.f, 0.f, 0.f, 0.f};
#pragma unroll
        for (int kc = 0; kc < 8; ++kc) {
            bf16x8 wf = ldb8(&wrow[kc * 32 + quad * 8]);
            acc = __builtin_amdgcn_mfma_f32_16x16x32_bf16(wf, xf[kc], acc, 0, 0, 0);
        }
        unsigned short hv[4];
#pragma unroll
        for (int r = 0; r < 4; ++r)
            hv[r] = f2bf(acc[r] + Bf[cv * CHH + o0 + quad * 4 + r]);
        if (cv == 1) {
            unsigned int lo = (unsigned int)hv[0] | ((unsigned int)hv[1] << 16);
            unsigned int hi = (unsigned int)hv[2] | ((unsigned int)hv[3] << 16);
            int src = (lane & 3) * 16 + (lane >> 2);
            unsigned int tlo = (unsigned int)__shfl((int)lo, src, 64);
            unsigned int thi = (unsigned int)__shfl((int)hi, src, 64);
            unsigned int* dst = (unsigned int*)&t2t[(size_t)(p0 + (lane >> 2)) * CHH +
                                                    o0 + (lane & 3) * 4];
            dst[0] = tlo;
            dst[1] = thi;
        } else {
            unsigned short* outp = (cv == 0) ? t1 : t3;
#pragma unroll
            for (int r = 0; r < 4; ++r)
                outp[(size_t)(o0 + quad * 4 + r) * NN + p0 + m] = hv[r];
        }
    }
}

// ---------------------------------------------------------------------------
// Kernel 4: generic bf16 tiled transpose (proven) — X3t only.
// ---------------------------------------------------------------------------
__launch_bounds__(256)
__global__ void transpose_kernel(const unsigned short* __restrict__ in,
                                 unsigned short* __restrict__ out, int R, int C) {
    int bz = blockIdx.z;
    in  += (size_t)bz * R * C;
    out += (size_t)bz * R * C;
    int c0 = blockIdx.x * 64, r0 = blockIdx.y * 64;
    __shared__ unsigned short t[64][68];
    int flat = threadIdx.x;
#pragma unroll
    for (int tt = 0; tt < 16; ++tt) {
        int id = flat + tt * 256;
        int r = id >> 6, c = id & 63;
        t[c][r] = in[(size_t)(r0 + r) * C + c0 + c];
    }
    __syncthreads();
#pragma unroll
    for (int tt = 0; tt < 16; ++tt) {
        int id = flat + tt * 256;
        int c = id >> 6, r = id & 63;
        out[(size_t)(c0 + c) * R + r0 + r] = t[c][r];
    }
}

// ---------------------------------------------------------------------------
// Kernel 5 (pass A): colsum exp(S-K) (proven round 10: 32-u waves, LDS-staged
// swizzled theta tiles, 8 i-chunks, grid 1024).
// ---------------------------------------------------------------------------
__launch_bounds__(256)
__global__ void stats_mfma_kernel(const unsigned short* __restrict__ T1b,
                                  const unsigned short* __restrict__ T2t,
                                  float* __restrict__ Lpart) {
    int blk = blockIdx.x;
    int b = (blk & 7) >> 1;
    int rest = (blk >> 3) * 2 + (blk & 1);   // 0..255 = strip*8 + iq
    int strip = rest >> 3, iq = rest & 7;
    int ibase = iq * 512;
    int flat = threadIdx.x;
    int w = flat >> 6, lane = flat & 63, m = lane & 15, quad = lane >> 4;
    const unsigned short* A  = T1b + (size_t)b * CHH * NN;
    const unsigned short* Bt = T2t + (size_t)b * CHH * NN;
    __shared__ unsigned short th[64 * 128];   // theta tile, swizzled [i][chunk']

    int u0w = strip * 128 + w * 32;           // this wave's 32-u window
    bf16x8 bfr[2][4];
#pragma unroll
    for (int g = 0; g < 2; ++g)
#pragma unroll
        for (int kc = 0; kc < 4; ++kc)
            bfr[g][kc] = ldb8(&Bt[(size_t)(u0w + g * 16 + m) * CHH + kc * 32 + quad * 8]);

    float csum[2] = {0.f, 0.f};
    for (int t = 0; t < 8; ++t) {            // 8 i-tiles of 64 in this chunk
        int i0t = ibase + t * 64;
        __syncthreads();
#pragma unroll
        for (int i = 0; i < 4; ++i) {
            int sl = i * 256 + flat;
            int r = sl >> 4, ch = sl & 15;
            int c = ch ^ (r & 7);
            gload_lds16(&A[(size_t)(i0t + r) * CHH + c * 8], &th[sl * 8]);
        }
        __syncthreads();
#pragma unroll
        for (int s = 0; s < 4; ++s) {
            int irow = s * 16 + m;
            bf16x8 af[4];
#pragma unroll
            for (int kc = 0; kc < 4; ++kc) {
                int ch = (kc * 4 + quad) ^ (irow & 7);
                af[kc] = *(const bf16x8*)&th[irow * 128 + ch * 8];
            }
#pragma unroll
            for (int g = 0; g < 2; ++g) {
                f32x4 acc = {0.f, 0.f, 0.f, 0.f};
#pragma unroll
                for (int kc = 0; kc < 4; ++kc)
                    acc = __builtin_amdgcn_mfma_f32_16x16x32_bf16(af[kc], bfr[g][kc], acc, 0, 0, 0);
#pragma unroll
                for (int r = 0; r < 4; ++r)
                    csum[g] += __expf(acc[r] - KSHIFT);
            }
        }
    }
#pragma unroll
    for (int g = 0; g < 2; ++g) {
        csum[g] += __shfl_xor(csum[g], 16, 64);
        csum[g] += __shfl_xor(csum[g], 32, 64);
        if (lane < 16)
            Lpart[((size_t)iq * BB + b) * NN + u0w + g * 16 + m] = csum[g];
    }
}

// ---------------------------------------------------------------------------
// Kernel 6 (pass B): Y = P @ X3. i-tile 128 (each wave owns 32 rows); the
// 32 KB staged tile feeds 256 MFMAs/block; LL computed in-prologue from
// Lpart (lmerge deleted). u-split x4, grid 512. Machinery proven rounds 8-10.
// ---------------------------------------------------------------------------
__launch_bounds__(256)
__global__ void attn_mfma_kernel(const unsigned short* __restrict__ T1b,
                                 const unsigned short* __restrict__ T2t,
                                 const unsigned short* __restrict__ X3t,
                                 const float* __restrict__ Lpart,
                                 unsigned short* __restrict__ Yp0,
                                 unsigned short* __restrict__ Yp1,
                                 unsigned short* __restrict__ Yp2,
                                 unsigned short* __restrict__ Yp3) {
    int blk = blockIdx.x;
    int b = (blk & 7) >> 1;
    int rest = (blk >> 3) * 2 + (blk & 1);   // 0..127 = it*4 + uc
    int it = rest >> 2, uc = rest & 3;
    int i0 = it * 128;
    unsigned short* Yp = uc == 0 ? Yp0 : (uc == 1 ? Yp1 : (uc == 2 ? Yp2 : Yp3));
    int flat = threadIdx.x;                   // 0..255
    int w = flat >> 6, lane = flat & 63, m = lane & 15, quad = lane >> 4;
    const unsigned short* A  = T1b + (size_t)b * CHH * NN;
    const unsigned short* Bt = T2t + (size_t)b * CHH * NN;
    const unsigned short* X3 = X3t + (size_t)b * CHH * NN;

    __shared__ unsigned short bt[64 * 128];   // phi^T tile, swizzled [u][chunk']
    __shared__ unsigned short x3[128 * 64];   // X3 tile, swizzled [j][chunk']
    __shared__ unsigned short pT[4][2][16][40]; // wave-private P half-tiles
    __shared__ float llh[1024];               // this chunk's LL values

    int ubeg = uc * 1024;
#pragma unroll
    for (int k = 0; k < 4; ++k) {             // LL prologue (replaces lmerge)
        int idx = k * 256 + flat;
        int u = ubeg + idx;
        float s = 0.f;
#pragma unroll
        for (int c = 0; c < 8; ++c)
            s += Lpart[((size_t)c * BB + b) * NN + u];
        llh[idx] = logf(s) + KSHIFT;
    }

    int iw = i0 + w * 32;
    bf16x8 ath[2][4];
#pragma unroll
    for (int g = 0; g < 2; ++g)
#pragma unroll
        for (int kc = 0; kc < 4; ++kc)
            ath[g][kc] = ldb8(&A[(size_t)(iw + g * 16 + m) * CHH + kc * 32 + quad * 8]);
    f32x4 yacc[2][8];
#pragma unroll
    for (int g = 0; g < 2; ++g)
#pragma unroll
        for (int js = 0; js < 8; ++js) yacc[g][js] = (f32x4){0.f, 0.f, 0.f, 0.f};

    for (int u0 = ubeg; u0 < ubeg + 1024; u0 += 64) {
        __syncthreads();                      // prev tile reads done (+ llh 1st iter)
#pragma unroll
        for (int i = 0; i < 4; ++i) {         // stage Bt tile (16 KB)
            int sl = i * 256 + flat;
            int u = sl >> 4, ch = sl & 15;
            int c = ch ^ (u & 7);
            gload_lds16(&Bt[(size_t)(u0 + u) * CHH + c * 8], &bt[sl * 8]);
        }
#pragma unroll
        for (int i = 0; i < 4; ++i) {         // stage X3 tile (16 KB)
            int sl = i * 256 + flat;
            int j = sl >> 3, ch = sl & 7;
            int c = ch ^ (j & 7);
            gload_lds16(&X3[(size_t)j * NN + u0 + c * 8], &x3[sl * 8]);
        }
        __syncthreads();                      // staging visible
#pragma unroll
        for (int h = 0; h < 2; ++h) {         // two 32-u halves
            // ---- S phase: S(32i x 32u), exp, P -> wave-private LDS ----
#pragma unroll
            for (int su = 0; su < 2; ++su) {
                int u = h * 32 + su * 16 + m;
                f32x4 a0 = {0.f, 0.f, 0.f, 0.f}, a1 = {0.f, 0.f, 0.f, 0.f};
#pragma unroll
                for (int kc = 0; kc < 4; ++kc) {
                    int ch = (kc * 4 + quad) ^ (u & 7);
                    bf16x8 bf = *(const bf16x8*)&bt[u * 128 + ch * 8];
                    a0 = __builtin_amdgcn_mfma_f32_16x16x32_bf16(ath[0][kc], bf, a0, 0, 0, 0);
                    a1 = __builtin_amdgcn_mfma_f32_16x16x32_bf16(ath[1][kc], bf, a1, 0, 0, 0);
                }
                float ll = llh[u0 - ubeg + u];
#pragma unroll
                for (int r = 0; r < 4; ++r) {
                    pT[w][0][quad * 4 + r][su * 16 + m] = f2bf(__expf(a0[r] - ll));
                    pT[w][1][quad * 4 + r][su * 16 + m] = f2bf(__expf(a1[r] - ll));
                }
            }
            // ---- PV phase: Y(32i x 128j) += P_half @ X3_half ----
            bf16x8 pa0 = *(const bf16x8*)&pT[w][0][m][quad * 8];
            bf16x8 pa1 = *(const bf16x8*)&pT[w][1][m][quad * 8];
#pragma unroll
            for (int js = 0; js < 8; ++js) {
                int j = js * 16 + m;
                int ch = (h * 4 + quad) ^ (j & 7);
                bf16x8 xb = *(const bf16x8*)&x3[j * 64 + ch * 8];
                yacc[0][js] = __builtin_amdgcn_mfma_f32_16x16x32_bf16(pa0, xb, yacc[0][js], 0, 0, 0);
                yacc[1][js] = __builtin_amdgcn_mfma_f32_16x16x32_bf16(pa1, xb, yacc[1][js], 0, 0, 0);
            }
        }
    }
#pragma unroll
    for (int g = 0; g < 2; ++g)
#pragma unroll
        for (int js = 0; js < 8; ++js)
#pragma unroll
            for (int r = 0; r < 4; ++r)
                Yp[((size_t)b * NN + iw + g * 16 + quad * 4 + r) * CHH + js * 16 + m] =
                    f2bf(yacc[g][js][r]);
}

// ---------------------------------------------------------------------------
// Kernel 7: out = x + out_w @ (Yp0+Yp1+Yp2+Yp3)^T + out_b via MFMA
// (proven round 10; partials merged in the fp32 accumulator).
// ---------------------------------------------------------------------------
template <typename T>
__device__ __forceinline__ void outconv_body(const T* __restrict__ x,
                                             const unsigned short* __restrict__ Yp0,
                                             const unsigned short* __restrict__ Yp1,
                                             const unsigned short* __restrict__ Yp2,
                                             const unsigned short* __restrict__ Yp3,
                                             const unsigned short* __restrict__ OWb,
                                             const float* __restrict__ OBf,
                                             T* __restrict__ out) {
    int b = blockIdx.y;
    int p0 = blockIdx.x * 16;
    int flat = threadIdx.x;
    int w = flat >> 6, lane = flat & 63, m = lane & 15, quad = lane >> 4;
    size_t yoff = ((size_t)b * NN + p0 + m) * CHH;
    const unsigned short* yrows[4] = {Yp0 + yoff, Yp1 + yoff, Yp2 + yoff, Yp3 + yoff};
    bf16x8 yf[4][4];
#pragma unroll
    for (int pz = 0; pz < 4; ++pz)
#pragma unroll
        for (int kc = 0; kc < 4; ++kc)
            yf[pz][kc] = ldb8(&yrows[pz][kc * 32 + quad * 8]);
#pragma unroll
    for (int q = 0; q < 4; ++q) {
        int o0 = (w * 4 + q) * 16;
        const unsigned short* wrow = OWb + (size_t)(o0 + m) * CHH;
        f32x4 acc = {0.f, 0.f, 0.f, 0.f};
#pragma unroll
        for (int kc = 0; kc < 4; ++kc) {
            bf16x8 aw = ldb8(&wrow[kc * 32 + quad * 8]);
#pragma unroll
            for (int pz = 0; pz < 4; ++pz)
                acc = __builtin_amdgcn_mfma_f32_16x16x32_bf16(aw, yf[pz][kc], acc, 0, 0, 0);
        }
#pragma unroll
        for (int r = 0; r < 4; ++r) {
            int co = o0 + quad * 4 + r;
            size_t oi = ((size_t)b * CC + co) * NN + p0 + m;
            st_f(&out[oi], acc[r] + OBf[co] + to_f(x[oi]));
        }
    }
}

__launch_bounds__(256)
__global__ void outconv_mfma_kernel(const void* x,
                                    const unsigned short* __restrict__ Yp0,
                                    const unsigned short* __restrict__ Yp1,
                                    const unsigned short* __restrict__ Yp2,
                                    const unsigned short* __restrict__ Yp3,
                                    const unsigned short* __restrict__ OWb,
                                    const float* __restrict__ OBf,
                                    const int* __restrict__ flag, void* out) {
    if (*flag)
        outconv_body<float>((const float*)x, Yp0, Yp1, Yp2, Yp3, OWb, OBf, (float*)out);
    else
        outconv_body<__hip_bfloat16>((const __hip_bfloat16*)x, Yp0, Yp1, Yp2, Yp3, OWb, OBf,
                                     (__hip_bfloat16*)out);
}

extern "C" void kernel_launch(void* const* d_in, const int* in_sizes, int n_in,
                              void* d_out, int out_size, void* d_ws, size_t ws_size,
                              hipStream_t stream) {
    const void* x  = d_in[0];
    const void* tw = d_in[1];
    const void* tb = d_in[2];
    const void* fw = d_in[3];
    const void* fb = d_in[4];
    const void* gw = d_in[5];
    const void* gb = d_in[6];
    const void* ow = d_in[7];
    const void* ob = d_in[8];

    // Workspace (~30 MB): conv3 writes T1b natural, T2t fused-transposed,
    // T3b natural; transpose T3b -> X3t. Aliases: Yp0/Yp1 <- xt (dead after
    // conv3), Yp2 <- T3b (dead after the X3t transpose), Yp3 fresh.
    const size_t TE = (size_t)BB * CHH * NN;        // 2,097,152
    unsigned short* T1b = (unsigned short*)d_ws;
    unsigned short* T2t = T1b + TE;                 // phi transposed [p][o]
    unsigned short* X3t = T2t + TE;                 // g-view transposed [j][u]
    unsigned short* T3b = X3t + TE;                 // g natural (CH,N)
    unsigned short* xt  = T3b + TE;                 // 2*TE shorts (dead after conv3)
    unsigned short* Yp0 = xt;                       // alias
    unsigned short* Yp1 = xt + TE;                  // alias
    unsigned short* Yp2 = T3b;                      // alias (dead after transpose)
    unsigned short* Yp3 = xt + 2 * TE;              // fresh
    unsigned short* Wb  = Yp3 + TE;                 // 98304 shorts
    unsigned short* OWb = Wb + 98304;               // 32768 shorts
    float* Bf    = (float*)(OWb + 32768);           // 384
    float* OBf   = Bf + 384;                        // 256
    float* Lpart = OBf + 256;                       // 8 * BB * NN = 131072
    int*   Flag  = (int*)(Lpart + 131072);

    detect_kernel<<<1, 64, 0, stream>>>(tb, Flag);
    prep_kernel<<<dim3(515), 256, 0, stream>>>(tw, fw, gw, ow, tb, fb, gb, ob,
                                               Flag, Wb, OWb, Bf, OBf);
    xtrans_kernel<<<dim3(NN / 64, CC / 64, BB), 256, 0, stream>>>(x, Flag, xt);
    conv3_mfma_kernel<<<dim3(NN / 16, BB), 256, 0, stream>>>(xt, Wb, Bf, T1b, T2t, T3b);
    transpose_kernel<<<dim3(CHH / 64, NN / 64, BB), 256, 0, stream>>>(T3b, X3t, NN, CHH);
    stats_mfma_kernel<<<dim3(1024), 256, 0, stream>>>(T1b, T2t, Lpart);
    attn_mfma_kernel<<<dim3(512), 256, 0, stream>>>(T1b, T2t, X3t, Lpart, Yp0, Yp1, Yp2, Yp3);
    outconv_mfma_kernel<<<dim3(NN / 16, BB), 256, 0, stream>>>(x, Yp0, Yp1, Yp2, Yp3,
                                                               OWb, OBf, Flag, d_out);
}